// Round 1
// baseline (7602.211 us; speedup 1.0000x reference)
//
#include <hip/hip_runtime.h>
#include <math.h>

// Problem constants (NaViT encoder)
#define LNUM 2
#define BB   4
#define NN   2048
#define DIM  768
#define NH   12
#define DH   64
#define MLPD 3072

// ---------------------------------------------------------------------------
// LayerNorm over last dim (768). One block (256 thr) per row; each thread owns
// 3 elements cached in regs so in==out (in-place) is safe.
// ---------------------------------------------------------------------------
__global__ __launch_bounds__(256) void ln_kernel(const float* in, const float* g, float* out)
{
    const int row = blockIdx.x;
    const int tid = threadIdx.x;
    const float* rp = in + (size_t)row * DIM;
    float vals[3];
    float s = 0.f, s2 = 0.f;
#pragma unroll
    for (int k = 0; k < 3; k++) {
        float v = rp[tid + k * 256];
        vals[k] = v;
        s += v; s2 += v * v;
    }
#pragma unroll
    for (int o = 32; o; o >>= 1) {
        s  += __shfl_xor(s, o);
        s2 += __shfl_xor(s2, o);
    }
    __shared__ float red[8];
    const int wid = tid >> 6;
    if ((tid & 63) == 0) { red[wid] = s; red[wid + 4] = s2; }
    __syncthreads();
    s  = red[0] + red[1] + red[2] + red[3];
    s2 = red[4] + red[5] + red[6] + red[7];
    const float mean = s * (1.f / DIM);
    const float var  = s2 * (1.f / DIM) - mean * mean;
    const float inv  = rsqrtf(var + 1e-5f);
    float* op = out + (size_t)row * DIM;
#pragma unroll
    for (int k = 0; k < 3; k++)
        op[tid + k * 256] = (vals[k] - mean) * inv * g[tid + k * 256];
}

// ---------------------------------------------------------------------------
// FP32 GEMM: C[M,Nc] = act(A[M,K] @ B[K,Nc] + bias) + resid
// 64x64 tile, 256 threads, 4x4 microtile, K-tile 16. act: 0=none, 1=exact gelu
// ---------------------------------------------------------------------------
__global__ __launch_bounds__(256) void gemm_kernel(
    const float* __restrict__ A, const float* __restrict__ Bm,
    const float* __restrict__ bias, const float* resid, float* C,
    int M, int Nc, int K, int act)
{
    __shared__ float As[16][68];  // As[k][m], padded
    __shared__ float Bs[16][68];  // Bs[k][n], padded
    const int tid = threadIdx.x;
    const int tx = tid & 15, ty = tid >> 4;
    const int tileN = blockIdx.x * 64, tileM = blockIdx.y * 64;
    float acc[4][4] = {{0.f,0.f,0.f,0.f},{0.f,0.f,0.f,0.f},{0.f,0.f,0.f,0.f},{0.f,0.f,0.f,0.f}};

    const int ar = tid >> 2, ac4 = tid & 3;   // A tile: 64 rows x 4 float4
    const int br = tid >> 4, bc4 = tid & 15;  // B tile: 16 rows x 16 float4

    const float* Aptr = A + (size_t)(tileM + ar) * K + ac4 * 4;
    const float* Bptr = Bm + (size_t)br * Nc + tileN + bc4 * 4;

    for (int kt = 0; kt < K; kt += 16) {
        float4 a4 = *(const float4*)(Aptr + kt);
        float4 b4 = *(const float4*)(Bptr + (size_t)kt * Nc);
        As[ac4 * 4 + 0][ar] = a4.x;
        As[ac4 * 4 + 1][ar] = a4.y;
        As[ac4 * 4 + 2][ar] = a4.z;
        As[ac4 * 4 + 3][ar] = a4.w;
        *(float4*)&Bs[br][bc4 * 4] = b4;
        __syncthreads();
#pragma unroll
        for (int k = 0; k < 16; k++) {
            float4 av = *(const float4*)&As[k][ty * 4];
            float4 bv = *(const float4*)&Bs[k][tx * 4];
            acc[0][0] += av.x * bv.x; acc[0][1] += av.x * bv.y; acc[0][2] += av.x * bv.z; acc[0][3] += av.x * bv.w;
            acc[1][0] += av.y * bv.x; acc[1][1] += av.y * bv.y; acc[1][2] += av.y * bv.z; acc[1][3] += av.y * bv.w;
            acc[2][0] += av.z * bv.x; acc[2][1] += av.z * bv.y; acc[2][2] += av.z * bv.z; acc[2][3] += av.z * bv.w;
            acc[3][0] += av.w * bv.x; acc[3][1] += av.w * bv.y; acc[3][2] += av.w * bv.z; acc[3][3] += av.w * bv.w;
        }
        __syncthreads();
    }

    float4 bsv = make_float4(0.f, 0.f, 0.f, 0.f);
    if (bias) bsv = *(const float4*)&bias[tileN + tx * 4];
#pragma unroll
    for (int j = 0; j < 4; j++) {
        const int mrow = tileM + ty * 4 + j;
        const size_t coff = (size_t)mrow * Nc + tileN + tx * 4;
        float v0 = acc[j][0] + bsv.x;
        float v1 = acc[j][1] + bsv.y;
        float v2 = acc[j][2] + bsv.z;
        float v3 = acc[j][3] + bsv.w;
        if (act == 1) {
            v0 = 0.5f * v0 * (1.f + erff(v0 * 0.7071067811865476f));
            v1 = 0.5f * v1 * (1.f + erff(v1 * 0.7071067811865476f));
            v2 = 0.5f * v2 * (1.f + erff(v2 * 0.7071067811865476f));
            v3 = 0.5f * v3 * (1.f + erff(v3 * 0.7071067811865476f));
        }
        if (resid) {
            float4 rv = *(const float4*)(resid + coff);
            v0 += rv.x; v1 += rv.y; v2 += rv.z; v3 += rv.w;
        }
        *(float4*)(C + coff) = make_float4(v0, v1, v2, v3);
    }
}

// ---------------------------------------------------------------------------
// QK RMSNorm (over DH=64, *sqrt(64)*gamma) + 2D RoPE, in place.
// One wave per (b,n,h) row; lane = dh index. rowstride: 768 for q, 1536 for k.
// ---------------------------------------------------------------------------
__global__ __launch_bounds__(256) void rmsrope_kernel(
    float* X, int rowstride, const float* __restrict__ g,
    const int* __restrict__ h_idx, const int* __restrict__ w_idx)
{
    const int tid  = threadIdx.x;
    const int lane = tid & 63;
    const int r    = blockIdx.x * 4 + (tid >> 6);  // (b*N+n)*H + h
    const int h    = r % NH;
    const int bn   = r / NH;
    const size_t off = (size_t)bn * rowstride + h * DH + lane;

    float v  = X[off];
    float gv = g[h * DH + lane];

    float ss = v * v;
#pragma unroll
    for (int o = 32; o; o >>= 1) ss += __shfl_xor(ss, o);
    float nrm = fmaxf(sqrtf(ss), 1e-12f);
    float val = v / nrm * 8.0f * gv;  // sqrt(DH)=8

    // 2D rope: lanes 0..31 use h_idx, 32..63 use w_idx; within a 32-half,
    // rotate_half pairs lanes d <-> d+16; freq index = lane & 15 (dq = 16).
    const int idx = (lane < 32) ? h_idx[bn] : w_idx[bn];
    const int f   = lane & 15;
    const float th = (float)idx * powf(10000.f, -(float)f * (1.f / 16.f));
    const float sn = sinf(th), cs = cosf(th);
    const float partner = __shfl_xor(val, 16);
    const float outv = ((lane & 31) < 16) ? (val * cs - partner * sn)
                                          : (val * cs + partner * sn);
    X[off] = outv;
}

// ---------------------------------------------------------------------------
// Flash-style masked attention. grid (B*H, N/256), 256 thr; one thread per
// query row. K/V 64x64 tiles staged in LDS (broadcast reads). Online softmax
// in 16-key chunks to bound live registers. No 1/sqrt(d) scaling (QK-RMSNorm).
// ---------------------------------------------------------------------------
__global__ __launch_bounds__(256) void attn_kernel(
    const float* __restrict__ Q, const float* __restrict__ Kp,
    const float* __restrict__ Vp, const int* __restrict__ lengths,
    float* __restrict__ O)
{
    __shared__ float Ks[64][64];
    __shared__ float Vs[64][64];
    const int bh = blockIdx.x;
    const int b  = bh / NH;
    const int h  = bh % NH;
    const int i  = blockIdx.y * 256 + threadIdx.x;
    const int len = lengths[b];

    const size_t qoff = ((size_t)(b * NN + i)) * DIM + h * DH;
    float q[DH];
#pragma unroll
    for (int d4 = 0; d4 < 16; d4++) {
        float4 t = *(const float4*)&Q[qoff + d4 * 4];
        q[d4 * 4 + 0] = t.x; q[d4 * 4 + 1] = t.y; q[d4 * 4 + 2] = t.z; q[d4 * 4 + 3] = t.w;
    }
    float acc[DH];
#pragma unroll
    for (int d = 0; d < DH; d++) acc[d] = 0.f;
    float m = -3.4e38f, l = 0.f;

    const int tiles = (len + 63) >> 6;
    for (int t = 0; t < tiles; t++) {
        const int j0 = t * 64;
#pragma unroll
        for (int rr = 0; rr < 4; rr++) {
            int e4  = threadIdx.x + rr * 256;  // 0..1023 float4s
            int row = e4 >> 4, c4 = e4 & 15;
            size_t koff = ((size_t)(b * NN + j0 + row)) * (2 * DIM) + h * DH + c4 * 4;
            *(float4*)&Ks[row][c4 * 4] = *(const float4*)&Kp[koff];
            *(float4*)&Vs[row][c4 * 4] = *(const float4*)&Vp[koff];
        }
        __syncthreads();
        const int jmax = min(64, len - j0);
        for (int c = 0; c < 64; c += 16) {
            if (c >= jmax) break;
            float s[16];
            float cmax = -3.4e38f;
#pragma unroll
            for (int jj = 0; jj < 16; jj++) {
                const int j = c + jj;
                float dot = 0.f;
#pragma unroll
                for (int d4 = 0; d4 < 16; d4++) {
                    float4 kv = *(const float4*)&Ks[j][d4 * 4];
                    dot += q[d4 * 4 + 0] * kv.x + q[d4 * 4 + 1] * kv.y
                         + q[d4 * 4 + 2] * kv.z + q[d4 * 4 + 3] * kv.w;
                }
                s[jj] = (j < jmax) ? dot : -3.4e38f;
                cmax = fmaxf(cmax, s[jj]);
            }
            const float newm  = fmaxf(m, cmax);
            const float alpha = __expf(m - newm);
            l *= alpha;
#pragma unroll
            for (int d = 0; d < DH; d++) acc[d] *= alpha;
#pragma unroll
            for (int jj = 0; jj < 16; jj++) {
                const int j = c + jj;
                const float p = (j < jmax) ? __expf(s[jj] - newm) : 0.f;
                l += p;
#pragma unroll
                for (int d4 = 0; d4 < 16; d4++) {
                    float4 vv = *(const float4*)&Vs[j][d4 * 4];
                    acc[d4 * 4 + 0] += p * vv.x; acc[d4 * 4 + 1] += p * vv.y;
                    acc[d4 * 4 + 2] += p * vv.z; acc[d4 * 4 + 3] += p * vv.w;
                }
            }
            m = newm;
        }
        __syncthreads();
    }
    const float inv = 1.f / l;
    const size_t ooff = ((size_t)(b * NN + i)) * DIM + h * DH;
#pragma unroll
    for (int d4 = 0; d4 < 16; d4++) {
        *(float4*)&O[ooff + d4 * 4] = make_float4(
            acc[d4 * 4 + 0] * inv, acc[d4 * 4 + 1] * inv,
            acc[d4 * 4 + 2] * inv, acc[d4 * 4 + 3] * inv);
    }
}

// ---------------------------------------------------------------------------
// mask output: [B,N] -> 1.0/0.0 as f32
// ---------------------------------------------------------------------------
__global__ __launch_bounds__(256) void mask_kernel(const int* __restrict__ lengths, float* __restrict__ out)
{
    const int i = blockIdx.x * 256 + threadIdx.x;  // 0..8191
    const int b = i >> 11;
    const int n = i & (NN - 1);
    out[i] = (n < lengths[b]) ? 1.f : 0.f;
}

// ---------------------------------------------------------------------------
extern "C" void kernel_launch(void* const* d_in, const int* in_sizes, int n_in,
                              void* d_out, int out_size, void* d_ws, size_t ws_size,
                              hipStream_t stream)
{
    const float* patches    = (const float*)d_in[0];
    const float* pe_ln1_g   = (const float*)d_in[1];
    const float* pe_W       = (const float*)d_in[2];
    const float* pe_b       = (const float*)d_in[3];
    const float* pe_ln2_g   = (const float*)d_in[4];
    const float* attn_ln_g  = (const float*)d_in[5];
    const float* qn_g       = (const float*)d_in[6];
    const float* kn_g       = (const float*)d_in[7];
    const float* Wq         = (const float*)d_in[8];
    const float* Wkv        = (const float*)d_in[9];
    const float* Wo         = (const float*)d_in[10];
    const float* ff_ln_g    = (const float*)d_in[11];
    const float* W1         = (const float*)d_in[12];
    const float* b1         = (const float*)d_in[13];
    const float* W2         = (const float*)d_in[14];
    const float* b2         = (const float*)d_in[15];
    const float* final_ln_g = (const float*)d_in[16];
    const int*   h_idx      = (const int*)d_in[17];
    const int*   w_idx      = (const int*)d_in[18];
    const int*   lengths    = (const int*)d_in[19];

    float* out = (float*)d_out;
    float* ws  = (float*)d_ws;

    const size_t U = (size_t)BB * NN * DIM;  // 6,291,456 floats
    float* x   = out;        // residual stream lives in d_out
    float* xn  = ws;         // LN output / GEMM input
    float* qb  = ws + U;     // q [8192,768]
    float* kvb = ws + 2 * U; // kv [8192,1536] (2 units)
    float* aob = ws + 4 * U; // attn out [8192,768]
    float* hb  = ws + U;     // MLP hidden [8192,3072] = 4 units, reuses qb..aob
    // total ws use: 5U floats = ~126 MB

    const int ROWS = BB * NN;  // 8192
    dim3 blk(256);

    // patch embedding: LN -> GEMM(+bias) -> LN
    ln_kernel<<<ROWS, blk, 0, stream>>>(patches, pe_ln1_g, xn);
    gemm_kernel<<<dim3(DIM / 64, ROWS / 64), blk, 0, stream>>>(xn, pe_W, pe_b, nullptr, qb, ROWS, DIM, DIM, 0);
    ln_kernel<<<ROWS, blk, 0, stream>>>(qb, pe_ln2_g, x);

    for (int i = 0; i < LNUM; i++) {
        ln_kernel<<<ROWS, blk, 0, stream>>>(x, attn_ln_g + i * DIM, xn);
        gemm_kernel<<<dim3(DIM / 64, ROWS / 64), blk, 0, stream>>>(
            xn, Wq + (size_t)i * DIM * DIM, nullptr, nullptr, qb, ROWS, DIM, DIM, 0);
        gemm_kernel<<<dim3(2 * DIM / 64, ROWS / 64), blk, 0, stream>>>(
            xn, Wkv + (size_t)i * DIM * 2 * DIM, nullptr, nullptr, kvb, ROWS, 2 * DIM, DIM, 0);
        rmsrope_kernel<<<ROWS * NH / 4, blk, 0, stream>>>(qb, DIM, qn_g + i * NH * DH, h_idx, w_idx);
        rmsrope_kernel<<<ROWS * NH / 4, blk, 0, stream>>>(kvb, 2 * DIM, kn_g + i * NH * DH, h_idx, w_idx);
        attn_kernel<<<dim3(BB * NH, NN / 256), blk, 0, stream>>>(qb, kvb, kvb + DIM, lengths, aob);
        gemm_kernel<<<dim3(DIM / 64, ROWS / 64), blk, 0, stream>>>(
            aob, Wo + (size_t)i * DIM * DIM, nullptr, x, x, ROWS, DIM, DIM, 0);
        ln_kernel<<<ROWS, blk, 0, stream>>>(x, ff_ln_g + i * DIM, xn);
        gemm_kernel<<<dim3(MLPD / 64, ROWS / 64), blk, 0, stream>>>(
            xn, W1 + (size_t)i * DIM * MLPD, b1 + i * MLPD, nullptr, hb, ROWS, MLPD, DIM, 1);
        gemm_kernel<<<dim3(DIM / 64, ROWS / 64), blk, 0, stream>>>(
            hb, W2 + (size_t)i * MLPD * DIM, b2 + i * DIM, x, x, ROWS, DIM, MLPD, 0);
    }
    ln_kernel<<<ROWS, blk, 0, stream>>>(x, final_ln_g, out);  // in-place safe
    mask_kernel<<<ROWS / 256, blk, 0, stream>>>(lengths, out + U);
}

// Round 2
// 4260.773 us; speedup vs baseline: 1.7842x; 1.7842x over previous
//
#include <hip/hip_runtime.h>
#include <math.h>

// Problem constants (NaViT encoder)
#define LNUM 2
#define BB   4
#define NN   2048
#define DIM  768
#define NH   12
#define DH   64
#define MLPD 3072

typedef __attribute__((ext_vector_type(8))) short bf16x8;
typedef __attribute__((ext_vector_type(4))) float f32x4;

__device__ inline unsigned short f2bf(float f) {
    union { float f; unsigned u; } v; v.f = f;
    unsigned r = v.u + 0x7fff + ((v.u >> 16) & 1);  // RNE
    return (unsigned short)(r >> 16);
}

// ---------------------------------------------------------------------------
// LayerNorm over last dim (768). One block (256 thr) per row.
// ---------------------------------------------------------------------------
__global__ __launch_bounds__(256) void ln_kernel(const float* in, const float* g, float* out)
{
    const int row = blockIdx.x;
    const int tid = threadIdx.x;
    const float* rp = in + (size_t)row * DIM;
    float vals[3];
    float s = 0.f, s2 = 0.f;
#pragma unroll
    for (int k = 0; k < 3; k++) {
        float v = rp[tid + k * 256];
        vals[k] = v;
        s += v; s2 += v * v;
    }
#pragma unroll
    for (int o = 32; o; o >>= 1) {
        s  += __shfl_xor(s, o);
        s2 += __shfl_xor(s2, o);
    }
    __shared__ float red[8];
    const int wid = tid >> 6;
    if ((tid & 63) == 0) { red[wid] = s; red[wid + 4] = s2; }
    __syncthreads();
    s  = red[0] + red[1] + red[2] + red[3];
    s2 = red[4] + red[5] + red[6] + red[7];
    const float mean = s * (1.f / DIM);
    const float var  = s2 * (1.f / DIM) - mean * mean;
    const float inv  = rsqrtf(var + 1e-5f);
    float* op = out + (size_t)row * DIM;
#pragma unroll
    for (int k = 0; k < 3; k++)
        op[tid + k * 256] = (vals[k] - mean) * inv * g[tid + k * 256];
}

// ---------------------------------------------------------------------------
// FP32 GEMM: C[M,Nc] = act(A[M,K] @ B[K,Nc] + bias) + resid
// ---------------------------------------------------------------------------
__global__ __launch_bounds__(256) void gemm_kernel(
    const float* __restrict__ A, const float* __restrict__ Bm,
    const float* __restrict__ bias, const float* resid, float* C,
    int M, int Nc, int K, int act)
{
    __shared__ float As[16][68];
    __shared__ float Bs[16][68];
    const int tid = threadIdx.x;
    const int tx = tid & 15, ty = tid >> 4;
    const int tileN = blockIdx.x * 64, tileM = blockIdx.y * 64;
    float acc[4][4] = {{0.f,0.f,0.f,0.f},{0.f,0.f,0.f,0.f},{0.f,0.f,0.f,0.f},{0.f,0.f,0.f,0.f}};

    const int ar = tid >> 2, ac4 = tid & 3;
    const int br = tid >> 4, bc4 = tid & 15;

    const float* Aptr = A + (size_t)(tileM + ar) * K + ac4 * 4;
    const float* Bptr = Bm + (size_t)br * Nc + tileN + bc4 * 4;

    for (int kt = 0; kt < K; kt += 16) {
        float4 a4 = *(const float4*)(Aptr + kt);
        float4 b4 = *(const float4*)(Bptr + (size_t)kt * Nc);
        As[ac4 * 4 + 0][ar] = a4.x;
        As[ac4 * 4 + 1][ar] = a4.y;
        As[ac4 * 4 + 2][ar] = a4.z;
        As[ac4 * 4 + 3][ar] = a4.w;
        *(float4*)&Bs[br][bc4 * 4] = b4;
        __syncthreads();
#pragma unroll
        for (int k = 0; k < 16; k++) {
            float4 av = *(const float4*)&As[k][ty * 4];
            float4 bv = *(const float4*)&Bs[k][tx * 4];
            acc[0][0] += av.x * bv.x; acc[0][1] += av.x * bv.y; acc[0][2] += av.x * bv.z; acc[0][3] += av.x * bv.w;
            acc[1][0] += av.y * bv.x; acc[1][1] += av.y * bv.y; acc[1][2] += av.y * bv.z; acc[1][3] += av.y * bv.w;
            acc[2][0] += av.z * bv.x; acc[2][1] += av.z * bv.y; acc[2][2] += av.z * bv.z; acc[2][3] += av.z * bv.w;
            acc[3][0] += av.w * bv.x; acc[3][1] += av.w * bv.y; acc[3][2] += av.w * bv.z; acc[3][3] += av.w * bv.w;
        }
        __syncthreads();
    }

    float4 bsv = make_float4(0.f, 0.f, 0.f, 0.f);
    if (bias) bsv = *(const float4*)&bias[tileN + tx * 4];
#pragma unroll
    for (int j = 0; j < 4; j++) {
        const int mrow = tileM + ty * 4 + j;
        const size_t coff = (size_t)mrow * Nc + tileN + tx * 4;
        float v0 = acc[j][0] + bsv.x;
        float v1 = acc[j][1] + bsv.y;
        float v2 = acc[j][2] + bsv.z;
        float v3 = acc[j][3] + bsv.w;
        if (act == 1) {
            v0 = 0.5f * v0 * (1.f + erff(v0 * 0.7071067811865476f));
            v1 = 0.5f * v1 * (1.f + erff(v1 * 0.7071067811865476f));
            v2 = 0.5f * v2 * (1.f + erff(v2 * 0.7071067811865476f));
            v3 = 0.5f * v3 * (1.f + erff(v3 * 0.7071067811865476f));
        }
        if (resid) {
            float4 rv = *(const float4*)(resid + coff);
            v0 += rv.x; v1 += rv.y; v2 += rv.z; v3 += rv.w;
        }
        *(float4*)(C + coff) = make_float4(v0, v1, v2, v3);
    }
}

// ---------------------------------------------------------------------------
// QK RMSNorm + 2D RoPE. Reads fp32, writes bf16 to separate buffer.
// One wave per (b,n,h) row; lane = dh index.
// ---------------------------------------------------------------------------
__global__ __launch_bounds__(256) void rmsrope_kernel(
    const float* __restrict__ X, int rowstride, const float* __restrict__ g,
    const int* __restrict__ h_idx, const int* __restrict__ w_idx,
    unsigned short* __restrict__ Xbf, int outstride)
{
    const int tid  = threadIdx.x;
    const int lane = tid & 63;
    const int r    = blockIdx.x * 4 + (tid >> 6);  // (b*N+n)*H + h
    const int h    = r % NH;
    const int bn   = r / NH;

    float v  = X[(size_t)bn * rowstride + h * DH + lane];
    float gv = g[h * DH + lane];

    float ss = v * v;
#pragma unroll
    for (int o = 32; o; o >>= 1) ss += __shfl_xor(ss, o);
    float nrm = fmaxf(sqrtf(ss), 1e-12f);
    float val = v / nrm * 8.0f * gv;  // sqrt(DH)=8

    const int idx = (lane < 32) ? h_idx[bn] : w_idx[bn];
    const int f   = lane & 15;
    const float th = (float)idx * powf(10000.f, -(float)f * (1.f / 16.f));
    const float sn = sinf(th), cs = cosf(th);
    const float partner = __shfl_xor(val, 16);
    const float outv = ((lane & 31) < 16) ? (val * cs - partner * sn)
                                          : (val * cs + partner * sn);
    Xbf[(size_t)bn * outstride + h * DH + lane] = f2bf(outv);
}

// ---------------------------------------------------------------------------
// V fp32 -> bf16 (rowstride 1536, V block at given pointers)
// ---------------------------------------------------------------------------
__global__ __launch_bounds__(256) void vconvert_kernel(
    const float* __restrict__ V, unsigned short* __restrict__ Vbf)
{
    const int e4 = blockIdx.x * 256 + threadIdx.x;  // over 8192*192
    const int row = e4 / 192, c4 = e4 % 192;
    const float4 v = *(const float4*)&V[(size_t)row * 1536 + c4 * 4];
    unsigned a = (unsigned)f2bf(v.x) | ((unsigned)f2bf(v.y) << 16);
    unsigned b = (unsigned)f2bf(v.z) | ((unsigned)f2bf(v.w) << 16);
    uint2 o = make_uint2(a, b);
    *(uint2*)&Vbf[(size_t)row * 1536 + c4 * 4] = o;
}

// ---------------------------------------------------------------------------
// BF16 MFMA flash attention. Block = 256 thr = 4 waves, 64 queries/block
// (16 per wave). grid (B*H, N/64). K tile 64 keys in LDS [key][dim]; V tile
// transposed [dim][key]; P via per-wave LDS round-trip (C-layout -> A-layout).
// All LDS padded to stride 76 (152B) -> <=2-way bank aliasing.
// mfma_f32_16x16x32_bf16: A[m=lane&15][k=quad*8+j], B[k=quad*8+j][n=lane&15],
// C/D: col=lane&15, row=quad*4+reg.
// ---------------------------------------------------------------------------
__global__ __launch_bounds__(256) void attn_kernel(
    const unsigned short* __restrict__ Qb, const unsigned short* __restrict__ Kb,
    const unsigned short* __restrict__ Vb, const int* __restrict__ lengths,
    float* __restrict__ O)
{
    __shared__ unsigned short Ks[64][76];
    __shared__ unsigned short Vt[64][76];
    __shared__ unsigned short Ps[4][16][76];

    const int bh = blockIdx.x;
    const int b  = bh / NH;
    const int h  = bh % NH;
    const int qbase = blockIdx.y * 64;
    const int tid  = threadIdx.x;
    const int w    = tid >> 6;
    const int lane = tid & 63;
    const int lq   = lane & 15;
    const int quad = lane >> 4;
    const int len  = lengths[b];

    // Q A-fragments (16 queries per wave, m = lq)
    const int qrow = qbase + w * 16 + lq;
    const unsigned short* qp = Qb + ((size_t)(b * NN + qrow)) * DIM + h * DH + quad * 8;
    bf16x8 aq0 = *(const bf16x8*)(qp);
    bf16x8 aq1 = *(const bf16x8*)(qp + 32);

    f32x4 oacc[4];
#pragma unroll
    for (int t4 = 0; t4 < 4; t4++) oacc[t4] = (f32x4){0.f, 0.f, 0.f, 0.f};
    float m[4], l[4];
#pragma unroll
    for (int r = 0; r < 4; r++) { m[r] = -3.4e38f; l[r] = 0.f; }

    const int ntiles = (len + 63) >> 6;
    for (int t = 0; t < ntiles; t++) {
        const int j0 = t * 64;
        // ---- stage K [key][dim] and V transposed [dim][key] ----
#pragma unroll
        for (int rr = 0; rr < 2; rr++) {
            const int e   = tid + rr * 256;   // 0..511, 16B chunks
            const int row = e >> 3, c8 = e & 7;
            const size_t goff = ((size_t)(b * NN + j0 + row)) * (2 * DIM) + h * DH + c8 * 8;
            *(uint4*)&Ks[row][c8 * 8] = *(const uint4*)(Kb + goff);
            unsigned short vv[8];
            *(uint4*)vv = *(const uint4*)(Vb + goff);
#pragma unroll
            for (int i = 0; i < 8; i++) Vt[c8 * 8 + i][row] = vv[i];
        }
        __syncthreads();

        // ---- S = Q K^T (4 key-subtiles of 16) ----
        f32x4 s[4];
#pragma unroll
        for (int n = 0; n < 4; n++) {
            bf16x8 bk0 = *(const bf16x8*)&Ks[n * 16 + lq][quad * 8];
            bf16x8 bk1 = *(const bf16x8*)&Ks[n * 16 + lq][32 + quad * 8];
            f32x4 acc = (f32x4){0.f, 0.f, 0.f, 0.f};
            acc = __builtin_amdgcn_mfma_f32_16x16x32_bf16(aq0, bk0, acc, 0, 0, 0);
            acc = __builtin_amdgcn_mfma_f32_16x16x32_bf16(aq1, bk1, acc, 0, 0, 0);
            s[n] = acc;
        }
        // mask invalid keys (this lane's col = j0 + n*16 + lq)
#pragma unroll
        for (int n = 0; n < 4; n++) {
            if (j0 + n * 16 + lq >= len) {
#pragma unroll
                for (int r = 0; r < 4; r++) s[n][r] = -3.4e38f;
            }
        }
        // ---- online softmax ----
        float rmax[4];
#pragma unroll
        for (int r = 0; r < 4; r++)
            rmax[r] = fmaxf(fmaxf(s[0][r], s[1][r]), fmaxf(s[2][r], s[3][r]));
#pragma unroll
        for (int o = 1; o < 16; o <<= 1) {
#pragma unroll
            for (int r = 0; r < 4; r++) rmax[r] = fmaxf(rmax[r], __shfl_xor(rmax[r], o));
        }
        float alpha[4];
#pragma unroll
        for (int r = 0; r < 4; r++) {
            const float nm = fmaxf(m[r], rmax[r]);
            alpha[r] = __expf(m[r] - nm);
            m[r] = nm;
        }
        float rsum[4] = {0.f, 0.f, 0.f, 0.f};
#pragma unroll
        for (int n = 0; n < 4; n++) {
#pragma unroll
            for (int r = 0; r < 4; r++) {
                const float p = __expf(s[n][r] - m[r]);
                s[n][r] = p;
                rsum[r] += p;
            }
        }
#pragma unroll
        for (int o = 1; o < 16; o <<= 1) {
#pragma unroll
            for (int r = 0; r < 4; r++) rsum[r] += __shfl_xor(rsum[r], o);
        }
#pragma unroll
        for (int r = 0; r < 4; r++) l[r] = l[r] * alpha[r] + rsum[r];
#pragma unroll
        for (int t4 = 0; t4 < 4; t4++) {
#pragma unroll
            for (int r = 0; r < 4; r++) oacc[t4][r] *= alpha[r];
        }
        // ---- P: C-layout regs -> per-wave LDS -> A-layout frags ----
#pragma unroll
        for (int n = 0; n < 4; n++) {
#pragma unroll
            for (int r = 0; r < 4; r++)
                Ps[w][quad * 4 + r][n * 16 + lq] = f2bf(s[n][r]);
        }
        asm volatile("s_waitcnt lgkmcnt(0)" ::: "memory");
        bf16x8 ap0 = *(const bf16x8*)&Ps[w][lq][quad * 8];
        bf16x8 ap1 = *(const bf16x8*)&Ps[w][lq][32 + quad * 8];
        // ---- O += P V (4 dim-subtiles of 16) ----
#pragma unroll
        for (int t4 = 0; t4 < 4; t4++) {
            bf16x8 bv0 = *(const bf16x8*)&Vt[t4 * 16 + lq][quad * 8];
            bf16x8 bv1 = *(const bf16x8*)&Vt[t4 * 16 + lq][32 + quad * 8];
            oacc[t4] = __builtin_amdgcn_mfma_f32_16x16x32_bf16(ap0, bv0, oacc[t4], 0, 0, 0);
            oacc[t4] = __builtin_amdgcn_mfma_f32_16x16x32_bf16(ap1, bv1, oacc[t4], 0, 0, 0);
        }
        __syncthreads();
    }

    float invl[4];
#pragma unroll
    for (int r = 0; r < 4; r++) invl[r] = 1.f / l[r];
#pragma unroll
    for (int t4 = 0; t4 < 4; t4++) {
#pragma unroll
        for (int r = 0; r < 4; r++) {
            const int qr = qbase + w * 16 + quad * 4 + r;
            O[((size_t)(b * NN + qr)) * DIM + h * DH + t4 * 16 + lq] = oacc[t4][r] * invl[r];
        }
    }
}

// ---------------------------------------------------------------------------
__global__ __launch_bounds__(256) void mask_kernel(const int* __restrict__ lengths, float* __restrict__ out)
{
    const int i = blockIdx.x * 256 + threadIdx.x;
    const int b = i >> 11;
    const int n = i & (NN - 1);
    out[i] = (n < lengths[b]) ? 1.f : 0.f;
}

// ---------------------------------------------------------------------------
extern "C" void kernel_launch(void* const* d_in, const int* in_sizes, int n_in,
                              void* d_out, int out_size, void* d_ws, size_t ws_size,
                              hipStream_t stream)
{
    const float* patches    = (const float*)d_in[0];
    const float* pe_ln1_g   = (const float*)d_in[1];
    const float* pe_W       = (const float*)d_in[2];
    const float* pe_b       = (const float*)d_in[3];
    const float* pe_ln2_g   = (const float*)d_in[4];
    const float* attn_ln_g  = (const float*)d_in[5];
    const float* qn_g       = (const float*)d_in[6];
    const float* kn_g       = (const float*)d_in[7];
    const float* Wq         = (const float*)d_in[8];
    const float* Wkv        = (const float*)d_in[9];
    const float* Wo         = (const float*)d_in[10];
    const float* ff_ln_g    = (const float*)d_in[11];
    const float* W1         = (const float*)d_in[12];
    const float* b1         = (const float*)d_in[13];
    const float* W2         = (const float*)d_in[14];
    const float* b2         = (const float*)d_in[15];
    const float* final_ln_g = (const float*)d_in[16];
    const int*   h_idx      = (const int*)d_in[17];
    const int*   w_idx      = (const int*)d_in[18];
    const int*   lengths    = (const int*)d_in[19];

    float* out = (float*)d_out;
    float* ws  = (float*)d_ws;

    const size_t U = (size_t)BB * NN * DIM;  // 6,291,456 floats
    float* x   = out;        // residual stream lives in d_out
    float* xn  = ws;         // slot A: LN output / GEMM input
    float* qb  = ws + U;     // slot B: q fp32 [8192,768]
    float* kvb = ws + 2 * U; // slot C: kv fp32 [8192,1536]
    float* aob = ws + 4 * U; // slot D: attn out [8192,768]
    float* hb  = ws + U;     // MLP hidden [8192,3072], reuses B..D
    // bf16 overlays (stream-ordered reuse of dead fp32 slots):
    unsigned short* qbf  = (unsigned short*)ws;        // overlays A (xn dead after kv gemm)
    unsigned short* kvbf = (unsigned short*)(ws + U);  // overlays B (qb dead after rmsrope_q)

    const int ROWS = BB * NN;  // 8192
    dim3 blk(256);

    // patch embedding: LN -> GEMM(+bias) -> LN
    ln_kernel<<<ROWS, blk, 0, stream>>>(patches, pe_ln1_g, xn);
    gemm_kernel<<<dim3(DIM / 64, ROWS / 64), blk, 0, stream>>>(xn, pe_W, pe_b, nullptr, qb, ROWS, DIM, DIM, 0);
    ln_kernel<<<ROWS, blk, 0, stream>>>(qb, pe_ln2_g, x);

    for (int i = 0; i < LNUM; i++) {
        ln_kernel<<<ROWS, blk, 0, stream>>>(x, attn_ln_g + i * DIM, xn);
        gemm_kernel<<<dim3(DIM / 64, ROWS / 64), blk, 0, stream>>>(
            xn, Wq + (size_t)i * DIM * DIM, nullptr, nullptr, qb, ROWS, DIM, DIM, 0);
        gemm_kernel<<<dim3(2 * DIM / 64, ROWS / 64), blk, 0, stream>>>(
            xn, Wkv + (size_t)i * DIM * 2 * DIM, nullptr, nullptr, kvb, ROWS, 2 * DIM, DIM, 0);
        // q: fp32 qb -> bf16 qbf (overlays xn slot; xn dead now)
        rmsrope_kernel<<<ROWS * NH / 4, blk, 0, stream>>>(
            qb, DIM, qn_g + i * NH * DH, h_idx, w_idx, qbf, DIM);
        // k: fp32 kvb -> bf16 kvbf (overlays qb slot; qb dead after prev launch)
        rmsrope_kernel<<<ROWS * NH / 4, blk, 0, stream>>>(
            kvb, 2 * DIM, kn_g + i * NH * DH, h_idx, w_idx, kvbf, 2 * DIM);
        // v: fp32 -> bf16
        vconvert_kernel<<<ROWS * (DIM / 4) / 256, blk, 0, stream>>>(kvb + DIM, kvbf + DIM);
        attn_kernel<<<dim3(BB * NH, NN / 64), blk, 0, stream>>>(
            qbf, kvbf, kvbf + DIM, lengths, aob);
        gemm_kernel<<<dim3(DIM / 64, ROWS / 64), blk, 0, stream>>>(
            aob, Wo + (size_t)i * DIM * DIM, nullptr, x, x, ROWS, DIM, DIM, 0);
        ln_kernel<<<ROWS, blk, 0, stream>>>(x, ff_ln_g + i * DIM, xn);
        gemm_kernel<<<dim3(MLPD / 64, ROWS / 64), blk, 0, stream>>>(
            xn, W1 + (size_t)i * DIM * MLPD, b1 + i * MLPD, nullptr, hb, ROWS, MLPD, DIM, 1);
        gemm_kernel<<<dim3(DIM / 64, ROWS / 64), blk, 0, stream>>>(
            hb, W2 + (size_t)i * MLPD * DIM, b2 + i * DIM, x, x, ROWS, DIM, MLPD, 0);
    }
    ln_kernel<<<ROWS, blk, 0, stream>>>(x, final_ln_g, out);
    mask_kernel<<<ROWS / 256, blk, 0, stream>>>(lengths, out + U);
}

// Round 3
// 1303.567 us; speedup vs baseline: 5.8319x; 3.2685x over previous
//
#include <hip/hip_runtime.h>
#include <math.h>

// Problem constants (NaViT encoder)
#define LNUM 2
#define BB   4
#define NN   2048
#define DIM  768
#define NH   12
#define DH   64
#define MLPD 3072

typedef __attribute__((ext_vector_type(8))) short bf16x8;
typedef __attribute__((ext_vector_type(4))) float f32x4;
typedef unsigned short ushort_t;

__device__ __forceinline__ ushort_t f2bf(float f) {
    union { float f; unsigned u; } v; v.f = f;
    unsigned r = v.u + 0x7fff + ((v.u >> 16) & 1);  // RNE
    return (ushort_t)(r >> 16);
}
__device__ __forceinline__ float bf2f(ushort_t s) {
    union { unsigned u; float f; } v; v.u = ((unsigned)s) << 16;
    return v.f;
}
__device__ __forceinline__ void gld16(const void* g, void* l) {
    __builtin_amdgcn_global_load_lds(
        (const __attribute__((address_space(1))) void*)g,
        (__attribute__((address_space(3))) void*)l, 16, 0, 0);
}

// ---------------------------------------------------------------------------
// Weight convert + transpose: W fp32 [K,N] -> Wt bf16 [N,K]. 32x32 LDS tiles.
// ---------------------------------------------------------------------------
__global__ __launch_bounds__(256) void wconvert_kernel(
    const float* __restrict__ W, ushort_t* __restrict__ Wt, int K, int N)
{
    __shared__ ushort_t t[32][33];
    const int tx = threadIdx.x & 31, ty = threadIdx.x >> 5;  // ty 0..7
    const int nt = blockIdx.x * 32, kt = blockIdx.y * 32;
#pragma unroll
    for (int r = 0; r < 4; r++) {
        const int k = kt + ty + r * 8;
        t[ty + r * 8][tx] = f2bf(W[(size_t)k * N + nt + tx]);
    }
    __syncthreads();
#pragma unroll
    for (int r = 0; r < 4; r++) {
        const int n = nt + ty + r * 8;
        Wt[(size_t)n * K + kt + tx] = t[tx][ty + r * 8];
    }
}

// ---------------------------------------------------------------------------
// LayerNorm over last dim (768). One block (256 thr) per row. OT: float|ushort
// ---------------------------------------------------------------------------
template <typename OT>
__global__ __launch_bounds__(256) void ln_kernel(const float* in, const float* g, OT* out)
{
    const int row = blockIdx.x;
    const int tid = threadIdx.x;
    const float* rp = in + (size_t)row * DIM;
    float vals[3];
    float s = 0.f, s2 = 0.f;
#pragma unroll
    for (int k = 0; k < 3; k++) {
        float v = rp[tid + k * 256];
        vals[k] = v;
        s += v; s2 += v * v;
    }
#pragma unroll
    for (int o = 32; o; o >>= 1) {
        s  += __shfl_xor(s, o);
        s2 += __shfl_xor(s2, o);
    }
    __shared__ float red[8];
    const int wid = tid >> 6;
    if ((tid & 63) == 0) { red[wid] = s; red[wid + 4] = s2; }
    __syncthreads();
    s  = red[0] + red[1] + red[2] + red[3];
    s2 = red[4] + red[5] + red[6] + red[7];
    const float mean = s * (1.f / DIM);
    const float var  = s2 * (1.f / DIM) - mean * mean;
    const float inv  = rsqrtf(var + 1e-5f);
    OT* op = out + (size_t)row * DIM;
#pragma unroll
    for (int k = 0; k < 3; k++) {
        const float v = (vals[k] - mean) * inv * g[tid + k * 256];
        if constexpr (sizeof(OT) == 2) op[tid + k * 256] = f2bf(v);
        else                           op[tid + k * 256] = v;
    }
}

// ---------------------------------------------------------------------------
// BF16 MFMA GEMM (m97 structure): C[M,N] = act(A[M,K] @ Bt[N,K]^T + bias)+resid
// 128x128 tile, BK=32, 256 thr = 4 waves (2x2 of 64x64), 16x16x32 MFMA.
// Staging via global_load_lds width 16 (contiguous lane order).
// outbf: 1 -> C bf16, 0 -> C fp32. act: 1 -> exact GELU.
// ---------------------------------------------------------------------------
__global__ __launch_bounds__(256) void gemm_bf(
    const ushort_t* __restrict__ A, const ushort_t* __restrict__ Bt,
    const float* __restrict__ bias, const float* __restrict__ resid,
    void* __restrict__ Cv, int M, int N, int K, int outbf, int act)
{
    __shared__ ushort_t As[128 * 32];
    __shared__ ushort_t Bs[128 * 32];
    const int tid  = threadIdx.x;
    const int w    = tid >> 6, lane = tid & 63;
    const int lq   = lane & 15, quad = lane >> 4;
    const int wm   = w & 1, wn = w >> 1;
    const int tileM = blockIdx.y * 128, tileN = blockIdx.x * 128;

    // staging: 512 chunks of 16B per tile; chunk c -> row c>>2, k-offset (c&3)*8
    const int c0 = tid, c1 = tid + 256;
    const ushort_t* ag0 = A  + (size_t)(tileM + (c0 >> 2)) * K + (c0 & 3) * 8;
    const ushort_t* ag1 = A  + (size_t)(tileM + (c1 >> 2)) * K + (c1 & 3) * 8;
    const ushort_t* bg0 = Bt + (size_t)(tileN + (c0 >> 2)) * K + (c0 & 3) * 8;
    const ushort_t* bg1 = Bt + (size_t)(tileN + (c1 >> 2)) * K + (c1 & 3) * 8;
    ushort_t* al0 = As + (w * 64) * 8;          // wave-uniform LDS bases
    ushort_t* al1 = As + (256 + w * 64) * 8;
    ushort_t* bl0 = Bs + (w * 64) * 8;
    ushort_t* bl1 = Bs + (256 + w * 64) * 8;

    f32x4 acc[4][4];
#pragma unroll
    for (int m = 0; m < 4; m++)
#pragma unroll
        for (int n = 0; n < 4; n++) acc[m][n] = (f32x4){0.f, 0.f, 0.f, 0.f};

    for (int kt = 0; kt < K; kt += 32) {
        gld16(ag0 + kt, al0);
        gld16(ag1 + kt, al1);
        gld16(bg0 + kt, bl0);
        gld16(bg1 + kt, bl1);
        __syncthreads();  // drains vmcnt

        bf16x8 af[4], bf_[4];
#pragma unroll
        for (int m = 0; m < 4; m++)
            af[m] = *(const bf16x8*)&As[(wm * 64 + m * 16 + lq) * 32 + quad * 8];
#pragma unroll
        for (int n = 0; n < 4; n++)
            bf_[n] = *(const bf16x8*)&Bs[(wn * 64 + n * 16 + lq) * 32 + quad * 8];
#pragma unroll
        for (int n = 0; n < 4; n++)
#pragma unroll
            for (int m = 0; m < 4; m++)
                acc[m][n] = __builtin_amdgcn_mfma_f32_16x16x32_bf16(af[m], bf_[n], acc[m][n], 0, 0, 0);
        __syncthreads();
    }

    float* Cf = (float*)Cv;
    ushort_t* Cb = (ushort_t*)Cv;
#pragma unroll
    for (int m = 0; m < 4; m++) {
#pragma unroll
        for (int n = 0; n < 4; n++) {
            const int col = tileN + wn * 64 + n * 16 + lq;
            const float bv = bias ? bias[col] : 0.f;
#pragma unroll
            for (int r = 0; r < 4; r++) {
                const int row = tileM + wm * 64 + m * 16 + quad * 4 + r;
                float v = acc[m][n][r] + bv;
                if (act) v = 0.5f * v * (1.f + erff(v * 0.7071067811865476f));
                const size_t off = (size_t)row * N + col;
                if (resid) v += resid[off];
                if (outbf) Cb[off] = f2bf(v);
                else       Cf[off] = v;
            }
        }
    }
}

// ---------------------------------------------------------------------------
// QK RMSNorm + 2D RoPE, in-place on bf16. One wave per (b,n,h) row.
// ---------------------------------------------------------------------------
__global__ __launch_bounds__(256) void rmsrope_kernel(
    ushort_t* X, int rowstride, const float* __restrict__ g,
    const int* __restrict__ h_idx, const int* __restrict__ w_idx)
{
    const int tid  = threadIdx.x;
    const int lane = tid & 63;
    const int r    = blockIdx.x * 4 + (tid >> 6);  // (b*N+n)*H + h
    const int h    = r % NH;
    const int bn   = r / NH;
    const size_t off = (size_t)bn * rowstride + h * DH + lane;

    float v  = bf2f(X[off]);
    float gv = g[h * DH + lane];

    float ss = v * v;
#pragma unroll
    for (int o = 32; o; o >>= 1) ss += __shfl_xor(ss, o);
    float nrm = fmaxf(sqrtf(ss), 1e-12f);
    float val = v / nrm * 8.0f * gv;  // sqrt(DH)=8

    const int idx = (lane < 32) ? h_idx[bn] : w_idx[bn];
    const int f   = lane & 15;
    const float th = (float)idx * powf(10000.f, -(float)f * (1.f / 16.f));
    const float sn = sinf(th), cs = cosf(th);
    const float partner = __shfl_xor(val, 16);
    const float outv = ((lane & 31) < 16) ? (val * cs - partner * sn)
                                          : (val * cs + partner * sn);
    X[off] = f2bf(outv);
}

// ---------------------------------------------------------------------------
// BF16 MFMA flash attention. Block = 4 waves, 64 queries (16/wave).
// grid (B*H, N/64). Writes bf16 output.
// ---------------------------------------------------------------------------
__global__ __launch_bounds__(256) void attn_kernel(
    const ushort_t* __restrict__ Qb, const ushort_t* __restrict__ Kb,
    const ushort_t* __restrict__ Vb, const int* __restrict__ lengths,
    ushort_t* __restrict__ O)
{
    __shared__ ushort_t Ks[64][76];
    __shared__ ushort_t Vt[64][76];
    __shared__ ushort_t Ps[4][16][76];

    const int bh = blockIdx.x;
    const int b  = bh / NH;
    const int h  = bh % NH;
    const int qbase = blockIdx.y * 64;
    const int tid  = threadIdx.x;
    const int w    = tid >> 6;
    const int lane = tid & 63;
    const int lq   = lane & 15;
    const int quad = lane >> 4;
    const int len  = lengths[b];

    const int qrow = qbase + w * 16 + lq;
    const ushort_t* qp = Qb + ((size_t)(b * NN + qrow)) * DIM + h * DH + quad * 8;
    bf16x8 aq0 = *(const bf16x8*)(qp);
    bf16x8 aq1 = *(const bf16x8*)(qp + 32);

    f32x4 oacc[4];
#pragma unroll
    for (int t4 = 0; t4 < 4; t4++) oacc[t4] = (f32x4){0.f, 0.f, 0.f, 0.f};
    float m[4], l[4];
#pragma unroll
    for (int r = 0; r < 4; r++) { m[r] = -3.4e38f; l[r] = 0.f; }

    const int ntiles = (len + 63) >> 6;
    for (int t = 0; t < ntiles; t++) {
        const int j0 = t * 64;
#pragma unroll
        for (int rr = 0; rr < 2; rr++) {
            const int e   = tid + rr * 256;
            const int row = e >> 3, c8 = e & 7;
            const size_t goff = ((size_t)(b * NN + j0 + row)) * (2 * DIM) + h * DH + c8 * 8;
            *(uint4*)&Ks[row][c8 * 8] = *(const uint4*)(Kb + goff);
            ushort_t vv[8];
            *(uint4*)vv = *(const uint4*)(Vb + goff);
#pragma unroll
            for (int i = 0; i < 8; i++) Vt[c8 * 8 + i][row] = vv[i];
        }
        __syncthreads();

        f32x4 s[4];
#pragma unroll
        for (int n = 0; n < 4; n++) {
            bf16x8 bk0 = *(const bf16x8*)&Ks[n * 16 + lq][quad * 8];
            bf16x8 bk1 = *(const bf16x8*)&Ks[n * 16 + lq][32 + quad * 8];
            f32x4 acc = (f32x4){0.f, 0.f, 0.f, 0.f};
            acc = __builtin_amdgcn_mfma_f32_16x16x32_bf16(aq0, bk0, acc, 0, 0, 0);
            acc = __builtin_amdgcn_mfma_f32_16x16x32_bf16(aq1, bk1, acc, 0, 0, 0);
            s[n] = acc;
        }
#pragma unroll
        for (int n = 0; n < 4; n++) {
            if (j0 + n * 16 + lq >= len) {
#pragma unroll
                for (int r = 0; r < 4; r++) s[n][r] = -3.4e38f;
            }
        }
        float rmax[4];
#pragma unroll
        for (int r = 0; r < 4; r++)
            rmax[r] = fmaxf(fmaxf(s[0][r], s[1][r]), fmaxf(s[2][r], s[3][r]));
#pragma unroll
        for (int o = 1; o < 16; o <<= 1) {
#pragma unroll
            for (int r = 0; r < 4; r++) rmax[r] = fmaxf(rmax[r], __shfl_xor(rmax[r], o));
        }
        float alpha[4];
#pragma unroll
        for (int r = 0; r < 4; r++) {
            const float nm = fmaxf(m[r], rmax[r]);
            alpha[r] = __expf(m[r] - nm);
            m[r] = nm;
        }
        float rsum[4] = {0.f, 0.f, 0.f, 0.f};
#pragma unroll
        for (int n = 0; n < 4; n++) {
#pragma unroll
            for (int r = 0; r < 4; r++) {
                const float p = __expf(s[n][r] - m[r]);
                s[n][r] = p;
                rsum[r] += p;
            }
        }
#pragma unroll
        for (int o = 1; o < 16; o <<= 1) {
#pragma unroll
            for (int r = 0; r < 4; r++) rsum[r] += __shfl_xor(rsum[r], o);
        }
#pragma unroll
        for (int r = 0; r < 4; r++) l[r] = l[r] * alpha[r] + rsum[r];
#pragma unroll
        for (int t4 = 0; t4 < 4; t4++) {
#pragma unroll
            for (int r = 0; r < 4; r++) oacc[t4][r] *= alpha[r];
        }
#pragma unroll
        for (int n = 0; n < 4; n++) {
#pragma unroll
            for (int r = 0; r < 4; r++)
                Ps[w][quad * 4 + r][n * 16 + lq] = f2bf(s[n][r]);
        }
        asm volatile("s_waitcnt lgkmcnt(0)" ::: "memory");
        bf16x8 ap0 = *(const bf16x8*)&Ps[w][lq][quad * 8];
        bf16x8 ap1 = *(const bf16x8*)&Ps[w][lq][32 + quad * 8];
#pragma unroll
        for (int t4 = 0; t4 < 4; t4++) {
            bf16x8 bv0 = *(const bf16x8*)&Vt[t4 * 16 + lq][quad * 8];
            bf16x8 bv1 = *(const bf16x8*)&Vt[t4 * 16 + lq][32 + quad * 8];
            oacc[t4] = __builtin_amdgcn_mfma_f32_16x16x32_bf16(ap0, bv0, oacc[t4], 0, 0, 0);
            oacc[t4] = __builtin_amdgcn_mfma_f32_16x16x32_bf16(ap1, bv1, oacc[t4], 0, 0, 0);
        }
        __syncthreads();
    }

    float invl[4];
#pragma unroll
    for (int r = 0; r < 4; r++) invl[r] = 1.f / l[r];
#pragma unroll
    for (int t4 = 0; t4 < 4; t4++) {
#pragma unroll
        for (int r = 0; r < 4; r++) {
            const int qr = qbase + w * 16 + quad * 4 + r;
            O[((size_t)(b * NN + qr)) * DIM + h * DH + t4 * 16 + lq] = f2bf(oacc[t4][r] * invl[r]);
        }
    }
}

// ---------------------------------------------------------------------------
__global__ __launch_bounds__(256) void mask_kernel(const int* __restrict__ lengths, float* __restrict__ out)
{
    const int i = blockIdx.x * 256 + threadIdx.x;
    const int b = i >> 11;
    const int n = i & (NN - 1);
    out[i] = (n < lengths[b]) ? 1.f : 0.f;
}

// ---------------------------------------------------------------------------
extern "C" void kernel_launch(void* const* d_in, const int* in_sizes, int n_in,
                              void* d_out, int out_size, void* d_ws, size_t ws_size,
                              hipStream_t stream)
{
    const float* patches    = (const float*)d_in[0];
    const float* pe_ln1_g   = (const float*)d_in[1];
    const float* pe_W       = (const float*)d_in[2];
    const float* pe_b       = (const float*)d_in[3];
    const float* pe_ln2_g   = (const float*)d_in[4];
    const float* attn_ln_g  = (const float*)d_in[5];
    const float* qn_g       = (const float*)d_in[6];
    const float* kn_g       = (const float*)d_in[7];
    const float* Wq         = (const float*)d_in[8];
    const float* Wkv        = (const float*)d_in[9];
    const float* Wo         = (const float*)d_in[10];
    const float* ff_ln_g    = (const float*)d_in[11];
    const float* W1         = (const float*)d_in[12];
    const float* b1         = (const float*)d_in[13];
    const float* W2         = (const float*)d_in[14];
    const float* b2         = (const float*)d_in[15];
    const float* final_ln_g = (const float*)d_in[16];
    const int*   h_idx      = (const int*)d_in[17];
    const int*   w_idx      = (const int*)d_in[18];
    const int*   lengths    = (const int*)d_in[19];

    float* out = (float*)d_out;
    char*  p   = (char*)d_ws;

    const size_t MB = 1024 * 1024;
    // bf16 transposed weights: pe_W + per-layer {Wq, Wkv, Wo, W1, W2}
    ushort_t* wbf = (ushort_t*)p;                       // 29.5 MB
    ushort_t* peWt = wbf;
    size_t woff = (size_t)DIM * DIM;
    ushort_t* Wqt[LNUM], *Wkvt[LNUM], *Wot[LNUM], *W1t[LNUM], *W2t[LNUM];
    for (int i = 0; i < LNUM; i++) {
        Wqt[i]  = wbf + woff; woff += (size_t)DIM * DIM;
        Wkvt[i] = wbf + woff; woff += (size_t)DIM * 2 * DIM;
        Wot[i]  = wbf + woff; woff += (size_t)DIM * DIM;
        W1t[i]  = wbf + woff; woff += (size_t)DIM * MLPD;
        W2t[i]  = wbf + woff; woff += (size_t)MLPD * DIM;
    }
    ushort_t* xnbf = (ushort_t*)(p + 30 * MB);          // 12.6 MB
    // region R @43MB: qbf(13) | kvbf(26) | aob(13); hb + pe-fp32 overlay R
    ushort_t* qbf  = (ushort_t*)(p + 43 * MB);
    ushort_t* kvbf = (ushort_t*)(p + 56 * MB);
    ushort_t* aob  = (ushort_t*)(p + 82 * MB);
    ushort_t* hb   = (ushort_t*)(p + 43 * MB);          // [8192,3072] bf16, 50.3 MB
    float*    peF  = (float*)(p + 43 * MB);             // [8192,768] fp32, 25.2 MB

    const int ROWS = BB * NN;  // 8192
    dim3 blk(256);

    // ---- weight convert + transpose (bf16) ----
    wconvert_kernel<<<dim3(DIM / 32, DIM / 32), blk, 0, stream>>>(pe_W, peWt, DIM, DIM);
    for (int i = 0; i < LNUM; i++) {
        wconvert_kernel<<<dim3(DIM / 32, DIM / 32), blk, 0, stream>>>(
            Wq + (size_t)i * DIM * DIM, Wqt[i], DIM, DIM);
        wconvert_kernel<<<dim3(2 * DIM / 32, DIM / 32), blk, 0, stream>>>(
            Wkv + (size_t)i * DIM * 2 * DIM, Wkvt[i], DIM, 2 * DIM);
        wconvert_kernel<<<dim3(DIM / 32, DIM / 32), blk, 0, stream>>>(
            Wo + (size_t)i * DIM * DIM, Wot[i], DIM, DIM);
        wconvert_kernel<<<dim3(MLPD / 32, DIM / 32), blk, 0, stream>>>(
            W1 + (size_t)i * DIM * MLPD, W1t[i], DIM, MLPD);
        wconvert_kernel<<<dim3(DIM / 32, MLPD / 32), blk, 0, stream>>>(
            W2 + (size_t)i * MLPD * DIM, W2t[i], MLPD, DIM);
    }

    // ---- patch embedding: LN -> GEMM(+bias) -> LN ----
    ln_kernel<ushort_t><<<ROWS, blk, 0, stream>>>(patches, pe_ln1_g, xnbf);
    gemm_bf<<<dim3(DIM / 128, ROWS / 128), blk, 0, stream>>>(
        xnbf, peWt, pe_b, nullptr, peF, ROWS, DIM, DIM, 0, 0);
    ln_kernel<float><<<ROWS, blk, 0, stream>>>(peF, pe_ln2_g, out);

    float* x = out;  // residual stream lives in d_out
    for (int i = 0; i < LNUM; i++) {
        ln_kernel<ushort_t><<<ROWS, blk, 0, stream>>>(x, attn_ln_g + i * DIM, xnbf);
        gemm_bf<<<dim3(DIM / 128, ROWS / 128), blk, 0, stream>>>(
            xnbf, Wqt[i], nullptr, nullptr, qbf, ROWS, DIM, DIM, 1, 0);
        gemm_bf<<<dim3(2 * DIM / 128, ROWS / 128), blk, 0, stream>>>(
            xnbf, Wkvt[i], nullptr, nullptr, kvbf, ROWS, 2 * DIM, DIM, 1, 0);
        rmsrope_kernel<<<ROWS * NH / 4, blk, 0, stream>>>(
            qbf, DIM, qn_g + i * NH * DH, h_idx, w_idx);
        rmsrope_kernel<<<ROWS * NH / 4, blk, 0, stream>>>(
            kvbf, 2 * DIM, kn_g + i * NH * DH, h_idx, w_idx);
        attn_kernel<<<dim3(BB * NH, NN / 64), blk, 0, stream>>>(
            qbf, kvbf, kvbf + DIM, lengths, aob);
        gemm_bf<<<dim3(DIM / 128, ROWS / 128), blk, 0, stream>>>(
            aob, Wot[i], nullptr, x, x, ROWS, DIM, DIM, 0, 0);
        ln_kernel<ushort_t><<<ROWS, blk, 0, stream>>>(x, ff_ln_g + i * DIM, xnbf);
        gemm_bf<<<dim3(MLPD / 128, ROWS / 128), blk, 0, stream>>>(
            xnbf, W1t[i], b1 + i * MLPD, nullptr, hb, ROWS, MLPD, DIM, 1, 1);
        gemm_bf<<<dim3(DIM / 128, ROWS / 128), blk, 0, stream>>>(
            hb, W2t[i], b2 + i * DIM, x, x, ROWS, DIM, MLPD, 0, 0);
    }
    ln_kernel<float><<<ROWS, blk, 0, stream>>>(x, final_ln_g, out);
    mask_kernel<<<ROWS / 256, blk, 0, stream>>>(lengths, out + (size_t)ROWS * DIM);
}

// Round 4
// 1147.237 us; speedup vs baseline: 6.6265x; 1.1363x over previous
//
#include <hip/hip_runtime.h>
#include <math.h>

// Problem constants (NaViT encoder)
#define LNUM 2
#define BB   4
#define NN   2048
#define DIM  768
#define NH   12
#define DH   64
#define MLPD 3072

typedef __attribute__((ext_vector_type(8))) short bf16x8;
typedef __attribute__((ext_vector_type(4))) float f32x4;
typedef unsigned short ushort_t;

__device__ __forceinline__ ushort_t f2bf(float f) {
    union { float f; unsigned u; } v; v.f = f;
    unsigned r = v.u + 0x7fff + ((v.u >> 16) & 1);  // RNE
    return (ushort_t)(r >> 16);
}
__device__ __forceinline__ float bf2f(ushort_t s) {
    union { unsigned u; float f; } v; v.u = ((unsigned)s) << 16;
    return v.f;
}
__device__ __forceinline__ void gld16(const void* g, void* l) {
    __builtin_amdgcn_global_load_lds(
        (const __attribute__((address_space(1))) void*)g,
        (__attribute__((address_space(3))) void*)l, 16, 0, 0);
}

// ---------------------------------------------------------------------------
// Weight convert + transpose: W fp32 [K,N] -> Wt bf16 [N,K]. 32x32 LDS tiles.
// ---------------------------------------------------------------------------
__global__ __launch_bounds__(256) void wconvert_kernel(
    const float* __restrict__ W, ushort_t* __restrict__ Wt, int K, int N)
{
    __shared__ ushort_t t[32][33];
    const int tx = threadIdx.x & 31, ty = threadIdx.x >> 5;  // ty 0..7
    const int nt = blockIdx.x * 32, kt = blockIdx.y * 32;
#pragma unroll
    for (int r = 0; r < 4; r++) {
        const int k = kt + ty + r * 8;
        t[ty + r * 8][tx] = f2bf(W[(size_t)k * N + nt + tx]);
    }
    __syncthreads();
#pragma unroll
    for (int r = 0; r < 4; r++) {
        const int n = nt + ty + r * 8;
        Wt[(size_t)n * K + kt + tx] = t[tx][ty + r * 8];
    }
}

// ---------------------------------------------------------------------------
// LayerNorm over last dim (768). One block (256 thr) per row. OT: float|ushort
// ---------------------------------------------------------------------------
template <typename OT>
__global__ __launch_bounds__(256) void ln_kernel(const float* in, const float* g, OT* out)
{
    const int row = blockIdx.x;
    const int tid = threadIdx.x;
    const float* rp = in + (size_t)row * DIM;
    float vals[3];
    float s = 0.f, s2 = 0.f;
#pragma unroll
    for (int k = 0; k < 3; k++) {
        float v = rp[tid + k * 256];
        vals[k] = v;
        s += v; s2 += v * v;
    }
#pragma unroll
    for (int o = 32; o; o >>= 1) {
        s  += __shfl_xor(s, o);
        s2 += __shfl_xor(s2, o);
    }
    __shared__ float red[8];
    const int wid = tid >> 6;
    if ((tid & 63) == 0) { red[wid] = s; red[wid + 4] = s2; }
    __syncthreads();
    s  = red[0] + red[1] + red[2] + red[3];
    s2 = red[4] + red[5] + red[6] + red[7];
    const float mean = s * (1.f / DIM);
    const float var  = s2 * (1.f / DIM) - mean * mean;
    const float inv  = rsqrtf(var + 1e-5f);
    OT* op = out + (size_t)row * DIM;
#pragma unroll
    for (int k = 0; k < 3; k++) {
        const float v = (vals[k] - mean) * inv * g[tid + k * 256];
        if constexpr (sizeof(OT) == 2) op[tid + k * 256] = f2bf(v);
        else                           op[tid + k * 256] = v;
    }
}

// ---------------------------------------------------------------------------
// BF16 MFMA GEMM (m97 structure): C[M,N] = act(A[M,K] @ Bt[N,K]^T + bias)+resid
// 128x128 tile, BK=32, 256 thr = 4 waves (2x2 of 64x64), 16x16x32 MFMA.
// ---------------------------------------------------------------------------
__global__ __launch_bounds__(256) void gemm_bf(
    const ushort_t* __restrict__ A, const ushort_t* __restrict__ Bt,
    const float* __restrict__ bias, const float* __restrict__ resid,
    void* __restrict__ Cv, int M, int N, int K, int outbf, int act)
{
    __shared__ ushort_t As[128 * 32];
    __shared__ ushort_t Bs[128 * 32];
    const int tid  = threadIdx.x;
    const int w    = tid >> 6, lane = tid & 63;
    const int lq   = lane & 15, quad = lane >> 4;
    const int wm   = w & 1, wn = w >> 1;
    const int tileM = blockIdx.y * 128, tileN = blockIdx.x * 128;

    const int c0 = tid, c1 = tid + 256;
    const ushort_t* ag0 = A  + (size_t)(tileM + (c0 >> 2)) * K + (c0 & 3) * 8;
    const ushort_t* ag1 = A  + (size_t)(tileM + (c1 >> 2)) * K + (c1 & 3) * 8;
    const ushort_t* bg0 = Bt + (size_t)(tileN + (c0 >> 2)) * K + (c0 & 3) * 8;
    const ushort_t* bg1 = Bt + (size_t)(tileN + (c1 >> 2)) * K + (c1 & 3) * 8;
    ushort_t* al0 = As + (w * 64) * 8;
    ushort_t* al1 = As + (256 + w * 64) * 8;
    ushort_t* bl0 = Bs + (w * 64) * 8;
    ushort_t* bl1 = Bs + (256 + w * 64) * 8;

    f32x4 acc[4][4];
#pragma unroll
    for (int m = 0; m < 4; m++)
#pragma unroll
        for (int n = 0; n < 4; n++) acc[m][n] = (f32x4){0.f, 0.f, 0.f, 0.f};

    for (int kt = 0; kt < K; kt += 32) {
        gld16(ag0 + kt, al0);
        gld16(ag1 + kt, al1);
        gld16(bg0 + kt, bl0);
        gld16(bg1 + kt, bl1);
        __syncthreads();

        bf16x8 af[4], bf_[4];
#pragma unroll
        for (int m = 0; m < 4; m++)
            af[m] = *(const bf16x8*)&As[(wm * 64 + m * 16 + lq) * 32 + quad * 8];
#pragma unroll
        for (int n = 0; n < 4; n++)
            bf_[n] = *(const bf16x8*)&Bs[(wn * 64 + n * 16 + lq) * 32 + quad * 8];
#pragma unroll
        for (int n = 0; n < 4; n++)
#pragma unroll
            for (int m = 0; m < 4; m++)
                acc[m][n] = __builtin_amdgcn_mfma_f32_16x16x32_bf16(af[m], bf_[n], acc[m][n], 0, 0, 0);
        __syncthreads();
    }

    float* Cf = (float*)Cv;
    ushort_t* Cb = (ushort_t*)Cv;
#pragma unroll
    for (int m = 0; m < 4; m++) {
#pragma unroll
        for (int n = 0; n < 4; n++) {
            const int col = tileN + wn * 64 + n * 16 + lq;
            const float bv = bias ? bias[col] : 0.f;
#pragma unroll
            for (int r = 0; r < 4; r++) {
                const int row = tileM + wm * 64 + m * 16 + quad * 4 + r;
                float v = acc[m][n][r] + bv;
                if (act) v = 0.5f * v * (1.f + erff(v * 0.7071067811865476f));
                const size_t off = (size_t)row * N + col;
                if (resid) v += resid[off];
                if (outbf) Cb[off] = f2bf(v);
                else       Cf[off] = v;
            }
        }
    }
}

// ---------------------------------------------------------------------------
// QK RMSNorm + 2D RoPE, in-place on bf16. One wave per (b,n,h) row.
// ---------------------------------------------------------------------------
__global__ __launch_bounds__(256) void rmsrope_kernel(
    ushort_t* X, int rowstride, const float* __restrict__ g,
    const int* __restrict__ h_idx, const int* __restrict__ w_idx)
{
    const int tid  = threadIdx.x;
    const int lane = tid & 63;
    const int r    = blockIdx.x * 4 + (tid >> 6);  // (b*N+n)*H + h
    const int h    = r % NH;
    const int bn   = r / NH;
    const size_t off = (size_t)bn * rowstride + h * DH + lane;

    float v  = bf2f(X[off]);
    float gv = g[h * DH + lane];

    float ss = v * v;
#pragma unroll
    for (int o = 32; o; o >>= 1) ss += __shfl_xor(ss, o);
    float nrm = fmaxf(sqrtf(ss), 1e-12f);
    float val = v / nrm * 8.0f * gv;  // sqrt(DH)=8

    const int idx = (lane < 32) ? h_idx[bn] : w_idx[bn];
    const int f   = lane & 15;
    const float th = (float)idx * powf(10000.f, -(float)f * (1.f / 16.f));
    const float sn = sinf(th), cs = cosf(th);
    const float partner = __shfl_xor(val, 16);
    const float outv = ((lane & 31) < 16) ? (val * cs - partner * sn)
                                          : (val * cs + partner * sn);
    X[off] = f2bf(outv);
}

// ---------------------------------------------------------------------------
// BF16 MFMA flash attention, streaming softmax (fixed max = 0; valid because
// QK-RMSNorm bounds |s| <= 64 and exp(+-64) is in f32 range).
// Block = 4 waves, 64 queries (16/wave). grid (B*H, N/64).
// S^T = K*Q^T so each lane owns ONE query (col=lq): l is a lane-scalar,
// P-writes pack 4 keys -> ds_write_b64.
// K/V LDS tiles XOR-swizzled (chunk ^= (row&7)^((row>>3)&7)) -> conflict-free.
// ---------------------------------------------------------------------------
__global__ __launch_bounds__(256) void attn_kernel(
    const ushort_t* __restrict__ Qb, const ushort_t* __restrict__ Kb,
    const ushort_t* __restrict__ Vb, const int* __restrict__ lengths,
    ushort_t* __restrict__ O)
{
    __shared__ ushort_t Ks[64 * 64];    // [key][dim], swizzled 16B chunks
    __shared__ ushort_t Vt[64 * 64];    // [dim][key], swizzled 16B chunks
    __shared__ ushort_t Ps[4][16][76];  // per-wave P^T: [query][key], padded

    const int bh = blockIdx.x;
    const int b  = bh / NH;
    const int h  = bh % NH;
    const int qbase = blockIdx.y * 64;
    const int tid  = threadIdx.x;
    const int w    = tid >> 6;
    const int lane = tid & 63;
    const int lq   = lane & 15;
    const int quad = lane >> 4;
    const int len  = lengths[b];

    // Q fragment (B-operand of S^T; also A-layout): query=lq, dims quad*8+j
    const int qrow = qbase + w * 16 + lq;
    const ushort_t* qp = Qb + ((size_t)(b * NN + qrow)) * DIM + h * DH + quad * 8;
    bf16x8 aq0 = *(const bf16x8*)(qp);
    bf16x8 aq1 = *(const bf16x8*)(qp + 32);

    f32x4 oacc[4];
#pragma unroll
    for (int t4 = 0; t4 < 4; t4++) oacc[t4] = (f32x4){0.f, 0.f, 0.f, 0.f};
    float lsum = 0.f;

    const int ntiles = (len + 63) >> 6;
    for (int t = 0; t < ntiles; t++) {
        const int j0 = t * 64;
        // ---- stage K [key][dim] and V^T [dim][key], both swizzled ----
#pragma unroll
        for (int rr = 0; rr < 2; rr++) {
            const int e  = tid + rr * 256;
            const int rk = e >> 3, c8 = e & 7;
            const size_t goff = ((size_t)(b * NN + j0 + rk)) * (2 * DIM) + h * DH + c8 * 8;
            const int ksw = (c8 ^ (rk & 7) ^ ((rk >> 3) & 7)) & 7;
            *(uint4*)&Ks[rk * 64 + ksw * 8] = *(const uint4*)(Kb + goff);
            ushort_t vv[8];
            *(uint4*)vv = *(const uint4*)(Vb + goff);
#pragma unroll
            for (int j = 0; j < 8; j++) {
                const int d = c8 * 8 + j;
                const int vsw = ((rk >> 3) ^ (d & 7) ^ ((d >> 3) & 7)) & 7;
                Vt[d * 64 + vsw * 8 + (rk & 7)] = vv[j];
            }
        }
        __syncthreads();

        // ---- S^T = K Q^T: rows = keys, cols = queries ----
        f32x4 s[4];
#pragma unroll
        for (int n = 0; n < 4; n++) {
            const int krow = n * 16 + lq;
            const int sw = (krow & 7) ^ ((krow >> 3) & 7);
            bf16x8 ak0 = *(const bf16x8*)&Ks[krow * 64 + ((quad ^ sw) & 7) * 8];
            bf16x8 ak1 = *(const bf16x8*)&Ks[krow * 64 + ((quad ^ sw ^ 4) & 7) * 8];
            f32x4 acc = (f32x4){0.f, 0.f, 0.f, 0.f};
            acc = __builtin_amdgcn_mfma_f32_16x16x32_bf16(ak0, aq0, acc, 0, 0, 0);
            acc = __builtin_amdgcn_mfma_f32_16x16x32_bf16(ak1, aq1, acc, 0, 0, 0);
            s[n] = acc;
        }

        // ---- p = exp(s), masked; stream into lsum (no max subtraction) ----
        float p[4][4];
#pragma unroll
        for (int n = 0; n < 4; n++) {
            const int keyb = j0 + n * 16 + quad * 4;
#pragma unroll
            for (int r = 0; r < 4; r++) {
                float pv = __expf(s[n][r]);
                pv = (keyb + r < len) ? pv : 0.f;
                p[n][r] = pv;
                lsum += pv;
            }
        }

        // ---- P^T -> per-wave LDS (b64 packed), then A-frag reads ----
#pragma unroll
        for (int n = 0; n < 4; n++) {
            const unsigned lo = (unsigned)f2bf(p[n][0]) | ((unsigned)f2bf(p[n][1]) << 16);
            const unsigned hi = (unsigned)f2bf(p[n][2]) | ((unsigned)f2bf(p[n][3]) << 16);
            *(uint2*)&Ps[w][lq][n * 16 + quad * 4] = make_uint2(lo, hi);
        }
        asm volatile("s_waitcnt lgkmcnt(0)" ::: "memory");
        bf16x8 ap0 = *(const bf16x8*)&Ps[w][lq][quad * 8];
        bf16x8 ap1 = *(const bf16x8*)&Ps[w][lq][32 + quad * 8];

        // ---- O += P V ----
#pragma unroll
        for (int t4 = 0; t4 < 4; t4++) {
            const int vrow = t4 * 16 + lq;
            const int sw = (vrow & 7) ^ ((vrow >> 3) & 7);
            bf16x8 bv0 = *(const bf16x8*)&Vt[vrow * 64 + ((quad ^ sw) & 7) * 8];
            bf16x8 bv1 = *(const bf16x8*)&Vt[vrow * 64 + ((quad ^ sw ^ 4) & 7) * 8];
            oacc[t4] = __builtin_amdgcn_mfma_f32_16x16x32_bf16(ap0, bv0, oacc[t4], 0, 0, 0);
            oacc[t4] = __builtin_amdgcn_mfma_f32_16x16x32_bf16(ap1, bv1, oacc[t4], 0, 0, 0);
        }
        __syncthreads();
    }

    // lane's lsum covers query lq's keys at this quad; reduce across quads
    lsum += __shfl_xor(lsum, 16);
    lsum += __shfl_xor(lsum, 32);
    // output rows are queries quad*4+r; fetch their l from lanes lq=quad*4+r
    float invq[4];
#pragma unroll
    for (int r = 0; r < 4; r++) invq[r] = 1.f / __shfl(lsum, quad * 4 + r);

#pragma unroll
    for (int t4 = 0; t4 < 4; t4++) {
#pragma unroll
        for (int r = 0; r < 4; r++) {
            const int qr = qbase + w * 16 + quad * 4 + r;
            O[((size_t)(b * NN + qr)) * DIM + h * DH + t4 * 16 + lq] = f2bf(oacc[t4][r] * invq[r]);
        }
    }
}

// ---------------------------------------------------------------------------
__global__ __launch_bounds__(256) void mask_kernel(const int* __restrict__ lengths, float* __restrict__ out)
{
    const int i = blockIdx.x * 256 + threadIdx.x;
    const int b = i >> 11;
    const int n = i & (NN - 1);
    out[i] = (n < lengths[b]) ? 1.f : 0.f;
}

// ---------------------------------------------------------------------------
extern "C" void kernel_launch(void* const* d_in, const int* in_sizes, int n_in,
                              void* d_out, int out_size, void* d_ws, size_t ws_size,
                              hipStream_t stream)
{
    const float* patches    = (const float*)d_in[0];
    const float* pe_ln1_g   = (const float*)d_in[1];
    const float* pe_W       = (const float*)d_in[2];
    const float* pe_b       = (const float*)d_in[3];
    const float* pe_ln2_g   = (const float*)d_in[4];
    const float* attn_ln_g  = (const float*)d_in[5];
    const float* qn_g       = (const float*)d_in[6];
    const float* kn_g       = (const float*)d_in[7];
    const float* Wq         = (const float*)d_in[8];
    const float* Wkv        = (const float*)d_in[9];
    const float* Wo         = (const float*)d_in[10];
    const float* ff_ln_g    = (const float*)d_in[11];
    const float* W1         = (const float*)d_in[12];
    const float* b1         = (const float*)d_in[13];
    const float* W2         = (const float*)d_in[14];
    const float* b2         = (const float*)d_in[15];
    const float* final_ln_g = (const float*)d_in[16];
    const int*   h_idx      = (const int*)d_in[17];
    const int*   w_idx      = (const int*)d_in[18];
    const int*   lengths    = (const int*)d_in[19];

    float* out = (float*)d_out;
    char*  p   = (char*)d_ws;

    const size_t MB = 1024 * 1024;
    ushort_t* wbf = (ushort_t*)p;                       // 29.5 MB
    ushort_t* peWt = wbf;
    size_t woff = (size_t)DIM * DIM;
    ushort_t* Wqt[LNUM], *Wkvt[LNUM], *Wot[LNUM], *W1t[LNUM], *W2t[LNUM];
    for (int i = 0; i < LNUM; i++) {
        Wqt[i]  = wbf + woff; woff += (size_t)DIM * DIM;
        Wkvt[i] = wbf + woff; woff += (size_t)DIM * 2 * DIM;
        Wot[i]  = wbf + woff; woff += (size_t)DIM * DIM;
        W1t[i]  = wbf + woff; woff += (size_t)DIM * MLPD;
        W2t[i]  = wbf + woff; woff += (size_t)MLPD * DIM;
    }
    ushort_t* xnbf = (ushort_t*)(p + 30 * MB);          // 12.6 MB
    ushort_t* qbf  = (ushort_t*)(p + 43 * MB);
    ushort_t* kvbf = (ushort_t*)(p + 56 * MB);
    ushort_t* aob  = (ushort_t*)(p + 82 * MB);
    ushort_t* hb   = (ushort_t*)(p + 43 * MB);          // [8192,3072] bf16
    float*    peF  = (float*)(p + 43 * MB);             // [8192,768] fp32

    const int ROWS = BB * NN;  // 8192
    dim3 blk(256);

    // ---- weight convert + transpose (bf16) ----
    wconvert_kernel<<<dim3(DIM / 32, DIM / 32), blk, 0, stream>>>(pe_W, peWt, DIM, DIM);
    for (int i = 0; i < LNUM; i++) {
        wconvert_kernel<<<dim3(DIM / 32, DIM / 32), blk, 0, stream>>>(
            Wq + (size_t)i * DIM * DIM, Wqt[i], DIM, DIM);
        wconvert_kernel<<<dim3(2 * DIM / 32, DIM / 32), blk, 0, stream>>>(
            Wkv + (size_t)i * DIM * 2 * DIM, Wkvt[i], DIM, 2 * DIM);
        wconvert_kernel<<<dim3(DIM / 32, DIM / 32), blk, 0, stream>>>(
            Wo + (size_t)i * DIM * DIM, Wot[i], DIM, DIM);
        wconvert_kernel<<<dim3(MLPD / 32, DIM / 32), blk, 0, stream>>>(
            W1 + (size_t)i * DIM * MLPD, W1t[i], DIM, MLPD);
        wconvert_kernel<<<dim3(DIM / 32, MLPD / 32), blk, 0, stream>>>(
            W2 + (size_t)i * MLPD * DIM, W2t[i], MLPD, DIM);
    }

    // ---- patch embedding: LN -> GEMM(+bias) -> LN ----
    ln_kernel<ushort_t><<<ROWS, blk, 0, stream>>>(patches, pe_ln1_g, xnbf);
    gemm_bf<<<dim3(DIM / 128, ROWS / 128), blk, 0, stream>>>(
        xnbf, peWt, pe_b, nullptr, peF, ROWS, DIM, DIM, 0, 0);
    ln_kernel<float><<<ROWS, blk, 0, stream>>>(peF, pe_ln2_g, out);

    float* x = out;  // residual stream lives in d_out
    for (int i = 0; i < LNUM; i++) {
        ln_kernel<ushort_t><<<ROWS, blk, 0, stream>>>(x, attn_ln_g + i * DIM, xnbf);
        gemm_bf<<<dim3(DIM / 128, ROWS / 128), blk, 0, stream>>>(
            xnbf, Wqt[i], nullptr, nullptr, qbf, ROWS, DIM, DIM, 1, 0);
        gemm_bf<<<dim3(2 * DIM / 128, ROWS / 128), blk, 0, stream>>>(
            xnbf, Wkvt[i], nullptr, nullptr, kvbf, ROWS, 2 * DIM, DIM, 1, 0);
        rmsrope_kernel<<<ROWS * NH / 4, blk, 0, stream>>>(
            qbf, DIM, qn_g + i * NH * DH, h_idx, w_idx);
        rmsrope_kernel<<<ROWS * NH / 4, blk, 0, stream>>>(
            kvbf, 2 * DIM, kn_g + i * NH * DH, h_idx, w_idx);
        attn_kernel<<<dim3(BB * NH, NN / 64), blk, 0, stream>>>(
            qbf, kvbf, kvbf + DIM, lengths, aob);
        gemm_bf<<<dim3(DIM / 128, ROWS / 128), blk, 0, stream>>>(
            aob, Wot[i], nullptr, x, x, ROWS, DIM, DIM, 0, 0);
        ln_kernel<ushort_t><<<ROWS, blk, 0, stream>>>(x, ff_ln_g + i * DIM, xnbf);
        gemm_bf<<<dim3(MLPD / 128, ROWS / 128), blk, 0, stream>>>(
            xnbf, W1t[i], b1 + i * MLPD, nullptr, hb, ROWS, MLPD, DIM, 1, 1);
        gemm_bf<<<dim3(DIM / 128, ROWS / 128), blk, 0, stream>>>(
            hb, W2t[i], b2 + i * DIM, x, x, ROWS, DIM, MLPD, 0, 0);
    }
    ln_kernel<float><<<ROWS, blk, 0, stream>>>(x, final_ln_g, out);
    mask_kernel<<<ROWS / 256, blk, 0, stream>>>(lengths, out + (size_t)ROWS * DIM);
}

// Round 5
// 1056.016 us; speedup vs baseline: 7.1990x; 1.0864x over previous
//
#include <hip/hip_runtime.h>
#include <math.h>

// Problem constants (NaViT encoder)
#define LNUM 2
#define BB   4
#define NN   2048
#define DIM  768
#define NH   12
#define DH   64
#define MLPD 3072
#define QKVD 2304   // fused q|k|v row stride

typedef __attribute__((ext_vector_type(8))) short bf16x8;
typedef __attribute__((ext_vector_type(4))) float f32x4;
typedef unsigned short ushort_t;

__device__ __forceinline__ ushort_t f2bf(float f) {
    union { float f; unsigned u; } v; v.f = f;
    unsigned r = v.u + 0x7fff + ((v.u >> 16) & 1);  // RNE
    return (ushort_t)(r >> 16);
}
__device__ __forceinline__ float bf2f(ushort_t s) {
    union { unsigned u; float f; } v; v.u = ((unsigned)s) << 16;
    return v.f;
}
__device__ __forceinline__ void gld16(const void* g, void* l) {
    __builtin_amdgcn_global_load_lds(
        (const __attribute__((address_space(1))) void*)g,
        (__attribute__((address_space(3))) void*)l, 16, 0, 0);
}

// ---------------------------------------------------------------------------
// Weight convert + transpose: W fp32 [K,N] -> Wt bf16 [N,K]. 32x32 LDS tiles.
// ---------------------------------------------------------------------------
__global__ __launch_bounds__(256) void wconvert_kernel(
    const float* __restrict__ W, ushort_t* __restrict__ Wt, int K, int N)
{
    __shared__ ushort_t t[32][33];
    const int tx = threadIdx.x & 31, ty = threadIdx.x >> 5;  // ty 0..7
    const int nt = blockIdx.x * 32, kt = blockIdx.y * 32;
#pragma unroll
    for (int r = 0; r < 4; r++) {
        const int k = kt + ty + r * 8;
        t[ty + r * 8][tx] = f2bf(W[(size_t)k * N + nt + tx]);
    }
    __syncthreads();
#pragma unroll
    for (int r = 0; r < 4; r++) {
        const int n = nt + ty + r * 8;
        Wt[(size_t)n * K + kt + tx] = t[tx][ty + r * 8];
    }
}

// ---------------------------------------------------------------------------
// LayerNorm over last dim (768). One block (256 thr) per row. OT: float|ushort
// ---------------------------------------------------------------------------
template <typename OT>
__global__ __launch_bounds__(256) void ln_kernel(const float* in, const float* g, OT* out)
{
    const int row = blockIdx.x;
    const int tid = threadIdx.x;
    const float* rp = in + (size_t)row * DIM;
    float vals[3];
    float s = 0.f, s2 = 0.f;
#pragma unroll
    for (int k = 0; k < 3; k++) {
        float v = rp[tid + k * 256];
        vals[k] = v;
        s += v; s2 += v * v;
    }
#pragma unroll
    for (int o = 32; o; o >>= 1) {
        s  += __shfl_xor(s, o);
        s2 += __shfl_xor(s2, o);
    }
    __shared__ float red[8];
    const int wid = tid >> 6;
    if ((tid & 63) == 0) { red[wid] = s; red[wid + 4] = s2; }
    __syncthreads();
    s  = red[0] + red[1] + red[2] + red[3];
    s2 = red[4] + red[5] + red[6] + red[7];
    const float mean = s * (1.f / DIM);
    const float var  = s2 * (1.f / DIM) - mean * mean;
    const float inv  = rsqrtf(var + 1e-5f);
    OT* op = out + (size_t)row * DIM;
#pragma unroll
    for (int k = 0; k < 3; k++) {
        const float v = (vals[k] - mean) * inv * g[tid + k * 256];
        if constexpr (sizeof(OT) == 2) op[tid + k * 256] = f2bf(v);
        else                           op[tid + k * 256] = v;
    }
}

// ---------------------------------------------------------------------------
// BF16 MFMA GEMM: C[M,N] = act(A[M,K] @ Bt[N,K]^T + bias) + resid
// TM x 128 tile (TM = 128 or 64), BK=32, 256 thr = 4 waves (2x2),
// 16x16x32 MFMA, global_load_lds width-16 staging.
// ---------------------------------------------------------------------------
template <int TM>
__global__ __launch_bounds__(256) void gemm_bf(
    const ushort_t* __restrict__ A, const ushort_t* __restrict__ Bt,
    const float* __restrict__ bias, const float* __restrict__ resid,
    void* __restrict__ Cv, int M, int N, int K, int outbf, int act)
{
    constexpr int MF = TM / 32;  // m-frags per wave: 4 (TM=128) or 2 (TM=64)
    __shared__ ushort_t As[TM * 32];
    __shared__ ushort_t Bs[128 * 32];
    const int tid  = threadIdx.x;
    const int w    = tid >> 6, lane = tid & 63;
    const int lq   = lane & 15, quad = lane >> 4;
    const int wm   = w & 1, wn = w >> 1;
    const int tileM = blockIdx.y * TM, tileN = blockIdx.x * 128;

    const int c0 = tid, c1 = tid + 256;
    const ushort_t* ag0 = A  + (size_t)(tileM + (c0 >> 2)) * K + (c0 & 3) * 8;
    const ushort_t* ag1 = A  + (size_t)(tileM + ((c1 >> 2) & (TM - 1))) * K + (c1 & 3) * 8;
    const ushort_t* bg0 = Bt + (size_t)(tileN + (c0 >> 2)) * K + (c0 & 3) * 8;
    const ushort_t* bg1 = Bt + (size_t)(tileN + (c1 >> 2)) * K + (c1 & 3) * 8;
    ushort_t* al0 = As + (w * 64) * 8;
    ushort_t* al1 = As + (256 + w * 64) * 8;
    ushort_t* bl0 = Bs + (w * 64) * 8;
    ushort_t* bl1 = Bs + (256 + w * 64) * 8;

    f32x4 acc[MF][4];
#pragma unroll
    for (int m = 0; m < MF; m++)
#pragma unroll
        for (int n = 0; n < 4; n++) acc[m][n] = (f32x4){0.f, 0.f, 0.f, 0.f};

    for (int kt = 0; kt < K; kt += 32) {
        gld16(ag0 + kt, al0);
        if constexpr (TM == 128) gld16(ag1 + kt, al1);
        gld16(bg0 + kt, bl0);
        gld16(bg1 + kt, bl1);
        __syncthreads();

        bf16x8 af[MF], bf_[4];
#pragma unroll
        for (int m = 0; m < MF; m++)
            af[m] = *(const bf16x8*)&As[(wm * (TM / 2) + m * 16 + lq) * 32 + quad * 8];
#pragma unroll
        for (int n = 0; n < 4; n++)
            bf_[n] = *(const bf16x8*)&Bs[(wn * 64 + n * 16 + lq) * 32 + quad * 8];
#pragma unroll
        for (int n = 0; n < 4; n++)
#pragma unroll
            for (int m = 0; m < MF; m++)
                acc[m][n] = __builtin_amdgcn_mfma_f32_16x16x32_bf16(af[m], bf_[n], acc[m][n], 0, 0, 0);
        __syncthreads();
    }

    float* Cf = (float*)Cv;
    ushort_t* Cb = (ushort_t*)Cv;
#pragma unroll
    for (int m = 0; m < MF; m++) {
#pragma unroll
        for (int n = 0; n < 4; n++) {
            const int col = tileN + wn * 64 + n * 16 + lq;
            const float bv = bias ? bias[col] : 0.f;
#pragma unroll
            for (int r = 0; r < 4; r++) {
                const int row = tileM + wm * (TM / 2) + m * 16 + quad * 4 + r;
                float v = acc[m][n][r] + bv;
                if (act) v = 0.5f * v * (1.f + erff(v * 0.7071067811865476f));
                const size_t off = (size_t)row * N + col;
                if (resid) v += resid[off];
                if (outbf) Cb[off] = f2bf(v);
                else       Cf[off] = v;
            }
        }
    }
}

// ---------------------------------------------------------------------------
// QK RMSNorm + 2D RoPE, in-place on bf16 at row stride QKVD.
// One wave per (b,n,h) row; lane = dh index. Base ptr selects q (col 0) or
// k (col 768) within the fused qkv buffer.
// ---------------------------------------------------------------------------
__global__ __launch_bounds__(256) void rmsrope_kernel(
    ushort_t* X, const float* __restrict__ g,
    const int* __restrict__ h_idx, const int* __restrict__ w_idx)
{
    const int tid  = threadIdx.x;
    const int lane = tid & 63;
    const int r    = blockIdx.x * 4 + (tid >> 6);  // (b*N+n)*H + h
    const int h    = r % NH;
    const int bn   = r / NH;
    const size_t off = (size_t)bn * QKVD + h * DH + lane;

    float v  = bf2f(X[off]);
    float gv = g[h * DH + lane];

    float ss = v * v;
#pragma unroll
    for (int o = 32; o; o >>= 1) ss += __shfl_xor(ss, o);
    float nrm = fmaxf(sqrtf(ss), 1e-12f);
    float val = v / nrm * 8.0f * gv;  // sqrt(DH)=8

    const int idx = (lane < 32) ? h_idx[bn] : w_idx[bn];
    const int f   = lane & 15;
    const float th = (float)idx * powf(10000.f, -(float)f * (1.f / 16.f));
    const float sn = sinf(th), cs = cosf(th);
    const float partner = __shfl_xor(val, 16);
    const float outv = ((lane & 31) < 16) ? (val * cs - partner * sn)
                                          : (val * cs + partner * sn);
    X[off] = f2bf(outv);
}

// ---------------------------------------------------------------------------
// V transpose: qkv v-block [B,N,H,DH] -> Vt [B,H,DH,N] bf16. 32x32 LDS tiles.
// grid (B*H, DH/32, N/32)
// ---------------------------------------------------------------------------
__global__ __launch_bounds__(256) void vtrans_kernel(
    const ushort_t* __restrict__ QKV, ushort_t* __restrict__ Vt)
{
    __shared__ ushort_t t[32][33];
    const int bh = blockIdx.x;
    const int b = bh / NH, h = bh % NH;
    const int d0 = blockIdx.y * 32, n0 = blockIdx.z * 32;
    const int tx = threadIdx.x & 31, ty = threadIdx.x >> 5;
#pragma unroll
    for (int r = 0; r < 4; r++) {
        const int n = n0 + ty + r * 8;
        t[ty + r * 8][tx] = QKV[(size_t)(b * NN + n) * QKVD + 2 * DIM + h * DH + d0 + tx];
    }
    __syncthreads();
#pragma unroll
    for (int r = 0; r < 4; r++) {
        const int d = d0 + ty + r * 8;
        Vt[((size_t)(b * NH + h) * DH + d) * NN + n0 + tx] = t[tx][ty + r * 8];
    }
}

// ---------------------------------------------------------------------------
// BF16 MFMA flash attention, streaming softmax (fixed max = 0; QK-RMSNorm
// bounds |s| <= 64, exp in f32 range). Block = 4 waves, 64 queries (16/wave).
// grid (B*H, N/64). S^T = K*Q^T; lane owns one query column.
// K and V^T staged via global_load_lds width-16; XOR swizzle applied on the
// GLOBAL chunk index (permutation within a 128B row) so LDS slots stay
// lane-contiguous (gld requirement) and frag reads are conflict-free.
//   slot e=(row*8+c8) holds row's chunk (c8 ^ hash(row)), hash=(row&7)^(row>>3)
// ---------------------------------------------------------------------------
__global__ __launch_bounds__(256) void attn_kernel(
    const ushort_t* __restrict__ QKV, const ushort_t* __restrict__ Vt_g,
    const int* __restrict__ lengths, ushort_t* __restrict__ O)
{
    __shared__ ushort_t Ks[64 * 64];
    __shared__ ushort_t Vs[64 * 64];
    __shared__ ushort_t Ps[4][16][76];

    const int bh = blockIdx.x;
    const int b  = bh / NH;
    const int h  = bh % NH;
    const int qbase = blockIdx.y * 64;
    const int tid  = threadIdx.x;
    const int w    = tid >> 6;
    const int lane = tid & 63;
    const int lq   = lane & 15;
    const int quad = lane >> 4;
    const int len  = lengths[b];

    // Q fragment: query=lq, dims quad*8+j
    const int qrow = qbase + w * 16 + lq;
    const ushort_t* qp = QKV + (size_t)(b * NN + qrow) * QKVD + h * DH + quad * 8;
    bf16x8 aq0 = *(const bf16x8*)(qp);
    bf16x8 aq1 = *(const bf16x8*)(qp + 32);

    // per-thread staging coords (2 chunks each for K and V)
    const int e0 = tid, e1 = tid + 256;
    const int r0 = e0 >> 3, c80 = e0 & 7;
    const int r1 = e1 >> 3, c81 = e1 & 7;
    const int g0 = (c80 ^ (r0 & 7) ^ (r0 >> 3)) & 7;
    const int g1 = (c81 ^ (r1 & 7) ^ (r1 >> 3)) & 7;
    const ushort_t* kg0 = QKV + (size_t)(b * NN + r0) * QKVD + DIM + h * DH + g0 * 8;
    const ushort_t* kg1 = QKV + (size_t)(b * NN + r1) * QKVD + DIM + h * DH + g1 * 8;
    const ushort_t* vg0 = Vt_g + ((size_t)(b * NH + h) * DH + r0) * NN + g0 * 8;
    const ushort_t* vg1 = Vt_g + ((size_t)(b * NH + h) * DH + r1) * NN + g1 * 8;
    ushort_t* kl0 = Ks + (w * 64) * 8;
    ushort_t* kl1 = Ks + (256 + w * 64) * 8;
    ushort_t* vl0 = Vs + (w * 64) * 8;
    ushort_t* vl1 = Vs + (256 + w * 64) * 8;

    f32x4 oacc[4];
#pragma unroll
    for (int t4 = 0; t4 < 4; t4++) oacc[t4] = (f32x4){0.f, 0.f, 0.f, 0.f};
    float lsum = 0.f;

    const int ntiles = (len + 63) >> 6;
    for (int t = 0; t < ntiles; t++) {
        const int j0 = t * 64;
        gld16(kg0 + (size_t)j0 * QKVD, kl0);
        gld16(kg1 + (size_t)j0 * QKVD, kl1);
        gld16(vg0 + j0, vl0);
        gld16(vg1 + j0, vl1);
        __syncthreads();

        // ---- S^T = K Q^T: rows = keys, cols = queries ----
        f32x4 s[4];
#pragma unroll
        for (int n = 0; n < 4; n++) {
            const int krow = n * 16 + lq;
            const int hashk = (krow & 7) ^ (krow >> 3);
            bf16x8 ak0 = *(const bf16x8*)&Ks[(krow * 8 + ((quad ^ hashk) & 7)) * 8];
            bf16x8 ak1 = *(const bf16x8*)&Ks[(krow * 8 + (((quad + 4) ^ hashk) & 7)) * 8];
            f32x4 acc = (f32x4){0.f, 0.f, 0.f, 0.f};
            acc = __builtin_amdgcn_mfma_f32_16x16x32_bf16(ak0, aq0, acc, 0, 0, 0);
            acc = __builtin_amdgcn_mfma_f32_16x16x32_bf16(ak1, aq1, acc, 0, 0, 0);
            s[n] = acc;
        }

        // ---- p = exp(s), masked; stream into lsum ----
        float p[4][4];
#pragma unroll
        for (int n = 0; n < 4; n++) {
            const int keyb = j0 + n * 16 + quad * 4;
#pragma unroll
            for (int r = 0; r < 4; r++) {
                float pv = __expf(s[n][r]);
                pv = (keyb + r < len) ? pv : 0.f;
                p[n][r] = pv;
                lsum += pv;
            }
        }

        // ---- P^T -> per-wave LDS (b64 packed), then A-frag reads ----
#pragma unroll
        for (int n = 0; n < 4; n++) {
            const unsigned lo = (unsigned)f2bf(p[n][0]) | ((unsigned)f2bf(p[n][1]) << 16);
            const unsigned hi = (unsigned)f2bf(p[n][2]) | ((unsigned)f2bf(p[n][3]) << 16);
            *(uint2*)&Ps[w][lq][n * 16 + quad * 4] = make_uint2(lo, hi);
        }
        asm volatile("s_waitcnt lgkmcnt(0)" ::: "memory");
        bf16x8 ap0 = *(const bf16x8*)&Ps[w][lq][quad * 8];
        bf16x8 ap1 = *(const bf16x8*)&Ps[w][lq][32 + quad * 8];

        // ---- O += P V ----
#pragma unroll
        for (int t4 = 0; t4 < 4; t4++) {
            const int vrow = t4 * 16 + lq;
            const int hashv = (vrow & 7) ^ (vrow >> 3);
            bf16x8 bv0 = *(const bf16x8*)&Vs[(vrow * 8 + ((quad ^ hashv) & 7)) * 8];
            bf16x8 bv1 = *(const bf16x8*)&Vs[(vrow * 8 + (((quad + 4) ^ hashv) & 7)) * 8];
            oacc[t4] = __builtin_amdgcn_mfma_f32_16x16x32_bf16(ap0, bv0, oacc[t4], 0, 0, 0);
            oacc[t4] = __builtin_amdgcn_mfma_f32_16x16x32_bf16(ap1, bv1, oacc[t4], 0, 0, 0);
        }
        __syncthreads();
    }

    lsum += __shfl_xor(lsum, 16);
    lsum += __shfl_xor(lsum, 32);
    float invq[4];
#pragma unroll
    for (int r = 0; r < 4; r++) invq[r] = 1.f / __shfl(lsum, quad * 4 + r);

#pragma unroll
    for (int t4 = 0; t4 < 4; t4++) {
#pragma unroll
        for (int r = 0; r < 4; r++) {
            const int qr = qbase + w * 16 + quad * 4 + r;
            O[((size_t)(b * NN + qr)) * DIM + h * DH + t4 * 16 + lq] = f2bf(oacc[t4][r] * invq[r]);
        }
    }
}

// ---------------------------------------------------------------------------
__global__ __launch_bounds__(256) void mask_kernel(const int* __restrict__ lengths, float* __restrict__ out)
{
    const int i = blockIdx.x * 256 + threadIdx.x;
    const int b = i >> 11;
    const int n = i & (NN - 1);
    out[i] = (n < lengths[b]) ? 1.f : 0.f;
}

// ---------------------------------------------------------------------------
extern "C" void kernel_launch(void* const* d_in, const int* in_sizes, int n_in,
                              void* d_out, int out_size, void* d_ws, size_t ws_size,
                              hipStream_t stream)
{
    const float* patches    = (const float*)d_in[0];
    const float* pe_ln1_g   = (const float*)d_in[1];
    const float* pe_W       = (const float*)d_in[2];
    const float* pe_b       = (const float*)d_in[3];
    const float* pe_ln2_g   = (const float*)d_in[4];
    const float* attn_ln_g  = (const float*)d_in[5];
    const float* qn_g       = (const float*)d_in[6];
    const float* kn_g       = (const float*)d_in[7];
    const float* Wq         = (const float*)d_in[8];
    const float* Wkv        = (const float*)d_in[9];
    const float* Wo         = (const float*)d_in[10];
    const float* ff_ln_g    = (const float*)d_in[11];
    const float* W1         = (const float*)d_in[12];
    const float* b1         = (const float*)d_in[13];
    const float* W2         = (const float*)d_in[14];
    const float* b2         = (const float*)d_in[15];
    const float* final_ln_g = (const float*)d_in[16];
    const int*   h_idx      = (const int*)d_in[17];
    const int*   w_idx      = (const int*)d_in[18];
    const int*   lengths    = (const int*)d_in[19];

    float* out = (float*)d_out;
    char*  p   = (char*)d_ws;

    const size_t MB = 1024 * 1024;
    // bf16 transposed weights (rows = output features, [N,K]):
    // peWt | per layer: Wqt (768 rows) + Wkvt (1536 rows, contiguous -> fused
    // 2304-row QKV weight), Wot, W1t, W2t
    ushort_t* wbf = (ushort_t*)p;                       // 29.5 MB
    ushort_t* peWt = wbf;
    size_t woff = (size_t)DIM * DIM;
    ushort_t* Wqkvt[LNUM], *Wot[LNUM], *W1t[LNUM], *W2t[LNUM];
    for (int i = 0; i < LNUM; i++) {
        Wqkvt[i] = wbf + woff; woff += (size_t)QKVD * DIM;  // q rows then kv rows
        Wot[i]   = wbf + woff; woff += (size_t)DIM * DIM;
        W1t[i]   = wbf + woff; woff += (size_t)DIM * MLPD;
        W2t[i]   = wbf + woff; woff += (size_t)MLPD * DIM;
    }
    ushort_t* xnbf = (ushort_t*)(p + 30 * MB);          // [8192,768]  12.6 MB
    ushort_t* qkv  = (ushort_t*)(p + 43 * MB);          // [8192,2304] 37.7 MB
    ushort_t* aob  = (ushort_t*)(p + 82 * MB);          // [8192,768]  12.6 MB
    ushort_t* hb   = (ushort_t*)(p + 43 * MB);          // [8192,3072] 50.3 MB (qkv dead)
    float*    peF  = (float*)(p + 43 * MB);             // [8192,768] fp32 (pe only)
    ushort_t* vtg  = (ushort_t*)(p + 96 * MB);          // [B,H,DH,N]  12.6 MB

    const int ROWS = BB * NN;  // 8192
    dim3 blk(256);

    // ---- weight convert + transpose (bf16) ----
    wconvert_kernel<<<dim3(DIM / 32, DIM / 32), blk, 0, stream>>>(pe_W, peWt, DIM, DIM);
    for (int i = 0; i < LNUM; i++) {
        wconvert_kernel<<<dim3(DIM / 32, DIM / 32), blk, 0, stream>>>(
            Wq + (size_t)i * DIM * DIM, Wqkvt[i], DIM, DIM);
        wconvert_kernel<<<dim3(2 * DIM / 32, DIM / 32), blk, 0, stream>>>(
            Wkv + (size_t)i * DIM * 2 * DIM, Wqkvt[i] + (size_t)DIM * DIM, DIM, 2 * DIM);
        wconvert_kernel<<<dim3(DIM / 32, DIM / 32), blk, 0, stream>>>(
            Wo + (size_t)i * DIM * DIM, Wot[i], DIM, DIM);
        wconvert_kernel<<<dim3(MLPD / 32, DIM / 32), blk, 0, stream>>>(
            W1 + (size_t)i * DIM * MLPD, W1t[i], DIM, MLPD);
        wconvert_kernel<<<dim3(DIM / 32, MLPD / 32), blk, 0, stream>>>(
            W2 + (size_t)i * MLPD * DIM, W2t[i], MLPD, DIM);
    }

    // ---- patch embedding: LN -> GEMM(+bias) -> LN ----
    ln_kernel<ushort_t><<<ROWS, blk, 0, stream>>>(patches, pe_ln1_g, xnbf);
    gemm_bf<64><<<dim3(DIM / 128, ROWS / 64), blk, 0, stream>>>(
        xnbf, peWt, pe_b, nullptr, peF, ROWS, DIM, DIM, 0, 0);
    ln_kernel<float><<<ROWS, blk, 0, stream>>>(peF, pe_ln2_g, out);

    float* x = out;  // residual stream lives in d_out
    for (int i = 0; i < LNUM; i++) {
        ln_kernel<ushort_t><<<ROWS, blk, 0, stream>>>(x, attn_ln_g + i * DIM, xnbf);
        // fused QKV GEMM -> [8192, 2304] bf16
        gemm_bf<128><<<dim3(QKVD / 128, ROWS / 128), blk, 0, stream>>>(
            xnbf, Wqkvt[i], nullptr, nullptr, qkv, ROWS, QKVD, DIM, 1, 0);
        rmsrope_kernel<<<ROWS * NH / 4, blk, 0, stream>>>(
            qkv, qn_g + i * NH * DH, h_idx, w_idx);          // q at col 0
        rmsrope_kernel<<<ROWS * NH / 4, blk, 0, stream>>>(
            qkv + DIM, kn_g + i * NH * DH, h_idx, w_idx);    // k at col 768
        vtrans_kernel<<<dim3(BB * NH, DH / 32, NN / 32), blk, 0, stream>>>(qkv, vtg);
        attn_kernel<<<dim3(BB * NH, NN / 64), blk, 0, stream>>>(
            qkv, vtg, lengths, aob);
        gemm_bf<64><<<dim3(DIM / 128, ROWS / 64), blk, 0, stream>>>(
            aob, Wot[i], nullptr, x, x, ROWS, DIM, DIM, 0, 0);
        ln_kernel<ushort_t><<<ROWS, blk, 0, stream>>>(x, ff_ln_g + i * DIM, xnbf);
        gemm_bf<128><<<dim3(MLPD / 128, ROWS / 128), blk, 0, stream>>>(
            xnbf, W1t[i], b1 + i * MLPD, nullptr, hb, ROWS, MLPD, DIM, 1, 1);
        gemm_bf<64><<<dim3(DIM / 128, ROWS / 64), blk, 0, stream>>>(
            hb, W2t[i], b2 + i * DIM, x, x, ROWS, DIM, MLPD, 0, 0);
    }
    ln_kernel<float><<<ROWS, blk, 0, stream>>>(x, final_ln_g, out);
    mask_kernel<<<ROWS / 256, blk, 0, stream>>>(lengths, out + (size_t)ROWS * DIM);
}